// Round 11
// baseline (1654.292 us; speedup 1.0000x reference)
//
#include <hip/hip_runtime.h>
#include <hip/hip_bf16.h>
#include <hip/hip_cooperative_groups.h>

namespace cg = cooperative_groups;

#define TPB 256
#define SH 6
#define BW 64  // nodes per bucket = 1<<SH; NBUK must be <= 1024 (N <= 65536)

typedef unsigned short u16;
typedef __attribute__((ext_vector_type(8))) __bf16 bf16x8;  // MFMA A/B frag (4 VGPRs)
typedef __attribute__((ext_vector_type(4))) float f32x4;    // MFMA C/D frag

// bf16 helpers: payload stored as bf16 (halves gather BW), accumulate in fp32.
__device__ __forceinline__ u16 f_to_bf(float f) {
    unsigned u = __float_as_uint(f);
    return (u16)((u + 0x7fff + ((u >> 16) & 1)) >> 16);  // RNE
}
__device__ __forceinline__ float4 bf4_to_f4(ushort4 v) {
    float4 r;
    r.x = __uint_as_float((unsigned)v.x << 16);
    r.y = __uint_as_float((unsigned)v.y << 16);
    r.z = __uint_as_float((unsigned)v.z << 16);
    r.w = __uint_as_float((unsigned)v.w << 16);
    return r;
}
__device__ __forceinline__ void facc(float4& a, float4 v) {
    a.x += v.x; a.y += v.y; a.z += v.z; a.w += v.w;
}
__device__ __forceinline__ float4 shfl_xor4(float4 v, int mask, int width) {
    v.x = __shfl_xor(v.x, mask, width);
    v.y = __shfl_xor(v.y, mask, width);
    v.z = __shfl_xor(v.z, mask, width);
    v.w = __shfl_xor(v.w, mask, width);
    return v;
}

template <int C>
__device__ __forceinline__ float4 gather_sum(const u16* __restrict__ HW,
                                             const int* __restrict__ col,
                                             int c0, int ps, int pe) {
    float4 a0 = make_float4(0.f, 0.f, 0.f, 0.f);
    float4 a1 = a0, a2 = a0, a3 = a0;
    int p = ps;
    for (; p + 4 <= pe; p += 4) {
        int j0 = col[p], j1 = col[p + 1], j2 = col[p + 2], j3 = col[p + 3];
        facc(a0, bf4_to_f4(*(const ushort4*)&HW[(size_t)j0 * C + c0]));
        facc(a1, bf4_to_f4(*(const ushort4*)&HW[(size_t)j1 * C + c0]));
        facc(a2, bf4_to_f4(*(const ushort4*)&HW[(size_t)j2 * C + c0]));
        facc(a3, bf4_to_f4(*(const ushort4*)&HW[(size_t)j3 * C + c0]));
    }
    for (; p < pe; p++) {
        int j = col[p];
        facc(a0, bf4_to_f4(*(const ushort4*)&HW[(size_t)j * C + c0]));
    }
    facc(a0, a1); facc(a2, a3); facc(a0, a2);
    return a0;
}

// ==================== MEGA (cooperative, single dispatch) ====================

struct MegaArgs {
    const float *X1, *X2;
    const int *e1, *e2;
    const float *W1, *b1, *W2, *b2, *W3, *b3;
    const float *Wa, *Wten, *Wb, *bt, *Wfc, *bfc, *Wsc, *bsc;
    float* out;
    int N, E, NBUK, gMM, g16, gB1, gB2;
    int *bcnt, *boff, *bcur;
    int *off0, *off1, *col0, *col1, *ebuf0, *ebuf1;
    float *dinv0, *dinv1;
    u16 *hwb0, *hwb1;
    float *bufB0, *bufB1;
    float *partial;   // >= G*16 floats
    float *cvecArr;   // 32 floats
};

// MFMA matmul phase: Y = bf16(dinv * (X @ W)); 64 nodes per virtual block.
template <int CIN, int COUT>
__device__ void mm_phase(const MegaArgs& A, char* shraw, const float* Xg0, const float* Xg1,
                         const float* W, u16* Y0, u16* Y1, int G, int bid, int tid) {
    constexpr int CINP = CIN + 8;
    constexpr int NT = COUT / 16;
    constexpr int KT = CIN / 32;
    u16* Xs = (u16*)shraw;
    u16* Wt = Xs + 64 * CINP;
    int lane = tid & 63, w = tid >> 6, m = lane & 15, quad = lane >> 4;
    for (int vb = bid; vb < 2 * A.gMM; vb += G) {
        int g = vb >= A.gMM;
        int nb0 = (vb - g * A.gMM) * 64;
        const float* X = g ? Xg1 : Xg0;
        const float* dinv = g ? A.dinv1 : A.dinv0;
        u16* Y = g ? Y1 : Y0;
        __syncthreads();  // protect LDS from previous iteration's readers
        for (int i = tid; i < 64 * (CIN / 4); i += TPB) {
            int nn = i / (CIN / 4), kc = i % (CIN / 4);
            float4 v = make_float4(0.f, 0.f, 0.f, 0.f);
            if (nb0 + nn < A.N) v = *(const float4*)&X[(size_t)(nb0 + nn) * CIN + 4 * kc];
            ushort4 b;
            b.x = f_to_bf(v.x); b.y = f_to_bf(v.y); b.z = f_to_bf(v.z); b.w = f_to_bf(v.w);
            *(ushort4*)&Xs[nn * CINP + 4 * kc] = b;
        }
        for (int i = tid; i < CIN * (COUT / 4); i += TPB) {
            int k = i / (COUT / 4), nc4 = i % (COUT / 4);
            float4 v = *(const float4*)&W[(size_t)k * COUT + 4 * nc4];
            Wt[(4 * nc4 + 0) * CINP + k] = f_to_bf(v.x);
            Wt[(4 * nc4 + 1) * CINP + k] = f_to_bf(v.y);
            Wt[(4 * nc4 + 2) * CINP + k] = f_to_bf(v.z);
            Wt[(4 * nc4 + 3) * CINP + k] = f_to_bf(v.w);
        }
        __syncthreads();
        f32x4 acc[NT];
#pragma unroll
        for (int t = 0; t < NT; t++) acc[t] = (f32x4){0.f, 0.f, 0.f, 0.f};
#pragma unroll
        for (int kt = 0; kt < KT; kt++) {
            int k0 = kt * 32 + quad * 8;
            bf16x8 a = *(const bf16x8*)&Xs[(w * 16 + m) * CINP + k0];
#pragma unroll
            for (int t = 0; t < NT; t++) {
                bf16x8 b = *(const bf16x8*)&Wt[(t * 16 + m) * CINP + k0];
                acc[t] = __builtin_amdgcn_mfma_f32_16x16x32_bf16(a, b, acc[t], 0, 0, 0);
            }
        }
#pragma unroll
        for (int r = 0; r < 4; r++) {
            int node = nb0 + w * 16 + quad * 4 + r;
            if (node < A.N) {
                float d = dinv[node];
#pragma unroll
                for (int t = 0; t < NT; t++)
                    Y[(size_t)node * COUT + t * 16 + m] = f_to_bf(acc[t][r] * d);
            }
        }
    }
}

template <int C, int SPLIT, bool RELU>
__device__ void agg_phase(const MegaArgs& A, const u16* HW0, const u16* HW1,
                          const float* bias, float* o0, float* o1, int G, int bid, int tid) {
    constexpr int CH = C / 4;
    constexpr int TPN = CH * SPLIT;
    for (int vb = bid; vb < 2 * A.g16; vb += G) {
        int g = vb >= A.g16;
        int flat = (vb - g * A.g16) * TPB + tid;
        const u16* HW = g ? HW1 : HW0;
        const int* off = g ? A.off1 : A.off0;
        const int* col = g ? A.col1 : A.col0;
        const float* dinv = g ? A.dinv1 : A.dinv0;
        float* outp = g ? o1 : o0;
        int node = flat / TPN;
        if (node >= A.N) continue;  // whole TPN group skips together (TPN divides 256)
        int part = flat % TPN;
        int sp = part / CH;
        int c0 = (part % CH) * 4;
        int s = off[node], e = off[node + 1];
        int len = e - s;
        int chunk = (len + SPLIT - 1) / SPLIT;
        int ps = s + sp * chunk;
        int pe = min(ps + chunk, e);
        float4 r = gather_sum<C>(HW, col, c0, ps, pe);
#pragma unroll
        for (int m = CH; m < TPN; m <<= 1) facc(r, shfl_xor4(r, m, TPN));
        if (sp == 0) {
            float di = dinv[node];
            float4 self = bf4_to_f4(*(const ushort4*)&HW[(size_t)node * C + c0]);
            float4 b4 = *(const float4*)&bias[c0];
            float4 o;
            o.x = di * (r.x + self.x) + b4.x;
            o.y = di * (r.y + self.y) + b4.y;
            o.z = di * (r.z + self.z) + b4.z;
            o.w = di * (r.w + self.w) + b4.w;
            if (RELU) {
                o.x = fmaxf(o.x, 0.f); o.y = fmaxf(o.y, 0.f);
                o.z = fmaxf(o.z, 0.f); o.w = fmaxf(o.w, 0.f);
            }
            *(float4*)&outp[(size_t)node * C + c0] = o;
        }
    }
}

__global__ __launch_bounds__(TPB, 2) void mega_kernel(MegaArgs A) {
    cg::grid_group grid = cg::this_grid();
    __shared__ __align__(16) char shraw[26624];
    const int tid = threadIdx.x;
    const int bid = blockIdx.x;
    const int G = gridDim.x;

    // P0: zero bucket counts
    for (int i = bid * TPB + tid; i < 2 * 1024; i += G * TPB) A.bcnt[i] = 0;
    grid.sync();

    // P1: bucket count (LDS histogram -> global atomics)
    {
        int* hist = (int*)shraw;
        for (int vb = bid; vb < 2 * A.gB1; vb += G) {
            int g = vb >= A.gB1;
            int cb = vb - g * A.gB1;
            const int* dst = (g ? A.e2 : A.e1) + A.E;
            int* bc = A.bcnt + g * 1024;
            for (int t = tid; t < 1024; t += TPB) hist[t] = 0;
            __syncthreads();
            int base = cb * 8192, end = min(base + 8192, A.E);
            for (int e = base + tid; e < end; e += TPB) atomicAdd(&hist[dst[e] >> SH], 1);
            __syncthreads();
            for (int t = tid; t < A.NBUK; t += TPB) {
                int h = hist[t];
                if (h) atomicAdd(&bc[t], h);
            }
            __syncthreads();
        }
    }
    grid.sync();

    // P2: bucket scan (blocks 0,1; 256 threads x 4 elems over 1024 bins)
    if (bid < 2) {
        int g = bid;
        const int* bc = A.bcnt + g * 1024;
        int* bo = A.boff + g * 1024;
        int* bu = A.bcur + g * 1024;
        int* sd = (int*)shraw;
        int i0 = tid * 4, vals[4], s = 0;
#pragma unroll
        for (int k = 0; k < 4; k++) { vals[k] = bc[i0 + k]; s += vals[k]; }
        sd[tid] = s;
        __syncthreads();
        for (int st = 1; st < TPB; st <<= 1) {
            int u = (tid >= st) ? sd[tid - st] : 0;
            __syncthreads();
            sd[tid] += u;
            __syncthreads();
        }
        int run = sd[tid] - s;
#pragma unroll
        for (int k = 0; k < 4; k++) { bo[i0 + k] = run; bu[i0 + k] = run; run += vals[k]; }
    }
    grid.sync();

    // P3: scatter edges into bucket regions (packed (src<<6)|(dst&63))
    {
        int* hist = (int*)shraw;
        for (int vb = bid; vb < 2 * A.gB2; vb += G) {
            int g = vb >= A.gB2;
            int cb = vb - g * A.gB2;
            const int* src = g ? A.e2 : A.e1;
            const int* dst = src + A.E;
            int* ebuf = g ? A.ebuf1 : A.ebuf0;
            int* bu = A.bcur + g * 1024;
            for (int t = tid; t < 1024; t += TPB) hist[t] = 0;
            __syncthreads();
            int base = cb * 4096;
            int pk[16], bk[16], rk[16];
#pragma unroll
            for (int k = 0; k < 16; k++) {
                int e = base + k * TPB + tid;
                bk[k] = -1;
                if (e < A.E) {
                    int s = src[e], d = dst[e];
                    int b = d >> SH;
                    bk[k] = b;
                    pk[k] = (s << SH) | (d & (BW - 1));
                    rk[k] = atomicAdd(&hist[b], 1);
                }
            }
            __syncthreads();
            for (int t = tid; t < A.NBUK; t += TPB) {
                int h = hist[t];
                hist[t] = h ? atomicAdd(&bu[t], h) : 0;
            }
            __syncthreads();
#pragma unroll
            for (int k = 0; k < 16; k++)
                if (bk[k] >= 0) ebuf[hist[bk[k]] + rk[k]] = pk[k];
            __syncthreads();
        }
    }
    grid.sync();

    // P4: per-bucket CSR finalize (histogram -> local scan -> off/dinv -> col fill)
    {
        int* h = (int*)shraw;
        int* nb = h + 64;
        int* nrank = nb + 64;
        for (int vb = bid; vb < 2 * A.NBUK; vb += G) {
            int g = vb >= A.NBUK;
            int b = vb - g * A.NBUK;
            const int* ebuf = g ? A.ebuf1 : A.ebuf0;
            int* off = g ? A.off1 : A.off0;
            float* dinv = g ? A.dinv1 : A.dinv0;
            int* col = g ? A.col1 : A.col0;
            if (tid < BW) h[tid] = 0;
            __syncthreads();
            int s = A.boff[g * 1024 + b], e = s + A.bcnt[g * 1024 + b];
            for (int i = s + tid; i < e; i += TPB)
                atomicAdd(&h[ebuf[i] & (BW - 1)], 1);
            __syncthreads();
            if (tid < BW) {
                int v = h[tid], x = v;
                for (int d = 1; d < BW; d <<= 1) {
                    int u = __shfl_up(x, d, 64);
                    if (tid >= d) x += u;
                }
                int base = s + x - v;
                nb[tid] = base;
                nrank[tid] = 0;
                int node = b * BW + tid;
                if (node < A.N) {
                    off[node] = base;
                    dinv[node] = rsqrtf((float)v + 1.0f);
                }
                if (node == 0) off[A.N] = A.E;
            }
            __syncthreads();
            for (int i = s + tid; i < e; i += TPB) {
                int p = ebuf[i];
                int lo = p & (BW - 1);
                int r = atomicAdd(&nrank[lo], 1);
                col[nb[lo] + r] = p >> SH;
            }
            __syncthreads();
        }
    }
    grid.sync();

    // P5..P10: three GCN layers
    mm_phase<96, 64>(A, shraw, A.X1, A.X2, A.W1, A.hwb0, A.hwb1, G, bid, tid);
    grid.sync();
    agg_phase<64, 1, true>(A, A.hwb0, A.hwb1, A.b1, A.bufB0, A.bufB1, G, bid, tid);
    grid.sync();
    mm_phase<64, 32>(A, shraw, A.bufB0, A.bufB1, A.W2, A.hwb0, A.hwb1, G, bid, tid);
    grid.sync();
    agg_phase<32, 2, true>(A, A.hwb0, A.hwb1, A.b2, A.bufB0, A.bufB1, G, bid, tid);
    grid.sync();
    mm_phase<32, 16>(A, shraw, A.bufB0, A.bufB1, A.W3, A.hwb0, A.hwb1, G, bid, tid);
    grid.sync();
    agg_phase<16, 4, false>(A, A.hwb0, A.hwb1, A.b3, A.bufB0, A.bufB1, G, bid, tid);
    grid.sync();

    // P11: column sums (per-block partials; block split across graphs)
    {
        float* sd = (float*)shraw;
        int half = G >> 1;
        int g = bid >= half;
        int bl = bid - g * half;
        const float* H = g ? A.bufB1 : A.bufB0;
        int c = tid & 15;
        int slot = bl * 16 + (tid >> 4);
        int stride = half * 16;
        float acc = 0.f;
        for (int node = slot; node < A.N; node += stride) acc += H[(size_t)node * 16 + c];
        __syncthreads();
        sd[tid] = acc;
        __syncthreads();
        if (tid < 16) {
            float s = 0.f;
            for (int t = tid; t < TPB; t += 16) s += sd[t];
            A.partial[bid * 16 + tid] = s;
        }
    }
    grid.sync();

    // P12: reduce partials -> cvec (block 0)
    if (bid == 0) {
        float* cs = (float*)shraw;  // 32 floats: mean colsum per graph
        int half = G >> 1;
        if (tid < 32) {
            int g = tid >> 4, c = tid & 15;
            float s = 0.f;
            for (int b = g * half; b < (g + 1) * half; b++) s += A.partial[b * 16 + c];
            cs[tid] = s / (float)A.N;
        }
        __syncthreads();
        if (tid < 32) {
            int g = tid >> 4, j = tid & 15;
            float acc = 0.f;
            for (int i = 0; i < 16; i++) acc += cs[g * 16 + i] * A.Wa[i * 16 + j];
            A.cvecArr[tid] = tanhf(acc);
        }
    }
    grid.sync();

    // P13: attention pooling (per-block partials)
    {
        float* sd = (float*)shraw;
        int half = G >> 1;
        int g = bid >= half;
        int bl = bid - g * half;
        const float* H = g ? A.bufB1 : A.bufB0;
        int c = tid & 15;
        float cv = A.cvecArr[g * 16 + c];
        int slot = bl * 16 + (tid >> 4);
        int stride = half * 16;
        float acc = 0.f;
        for (int node = slot; node < A.N; node += stride) {
            float x = H[(size_t)node * 16 + c];
            float p = x * cv;
            p += __shfl_xor(p, 1, 16);
            p += __shfl_xor(p, 2, 16);
            p += __shfl_xor(p, 4, 16);
            p += __shfl_xor(p, 8, 16);
            float s = 1.f / (1.f + __expf(-p));
            acc += s * x;
        }
        __syncthreads();
        sd[tid] = acc;
        __syncthreads();
        if (tid < 16) {
            float s = 0.f;
            for (int t = tid; t < TPB; t += 16) s += sd[t];
            A.partial[bid * 16 + tid] = s;
        }
    }
    grid.sync();

    // P14: reduce rep + tensor-network scoring (block 0)
    if (bid == 0) {
        float* sm = (float*)shraw;
        float* rep = sm;           // 32
        float* scores = sm + 32;   // 16
        float* tvec = sm + 48;     // 16
        int half = G >> 1;
        if (tid < 32) {
            int g = tid >> 4, c = tid & 15;
            float s = 0.f;
            for (int b = g * half; b < (g + 1) * half; b++) s += A.partial[b * 16 + c];
            rep[tid] = s;
        }
        __syncthreads();
        if (tid < 16) {
            float bil = 0.f;
            for (int i = 0; i < 16; i++) {
                float a = rep[i];
                for (int j = 0; j < 16; j++) bil += a * rep[16 + j] * A.Wten[(i * 16 + j) * 16 + tid];
            }
            float blk = 0.f;
            for (int m2 = 0; m2 < 16; m2++)
                blk += A.Wb[tid * 32 + m2] * rep[m2] + A.Wb[tid * 32 + 16 + m2] * rep[16 + m2];
            scores[tid] = fmaxf(bil + blk + A.bt[tid], 0.f);
        }
        __syncthreads();
        if (tid < 16) {
            float acc = A.bfc[tid];
            for (int k = 0; k < 16; k++) acc += scores[k] * A.Wfc[k * 16 + tid];
            tvec[tid] = tanhf(acc);
        }
        __syncthreads();
        if (tid == 0) {
            float acc = A.bsc[0];
            for (int j = 0; j < 16; j++) acc += tvec[j] * A.Wsc[j];
            A.out[0] = 1.f / (1.f + __expf(-acc));
        }
    }
}

// ==================== FALLBACK (proven 15-dispatch path) ====================

__global__ void bucket_count_kernel(const int* __restrict__ dst0, const int* __restrict__ dst1,
                                    int E, int* __restrict__ bcnt, int nbuk) {
    const int* dst = blockIdx.y ? dst1 : dst0;
    int* bc = bcnt + blockIdx.y * 1024;
    __shared__ int hist[1024];
    for (int t = threadIdx.x; t < 1024; t += TPB) hist[t] = 0;
    __syncthreads();
    int base = blockIdx.x * 8192;
    int end = min(base + 8192, E);
    for (int e = base + (int)threadIdx.x; e < end; e += TPB)
        atomicAdd(&hist[dst[e] >> SH], 1);
    __syncthreads();
    for (int t = threadIdx.x; t < nbuk; t += TPB) {
        int h = hist[t];
        if (h) atomicAdd(&bc[t], h);
    }
}

__global__ void bucket_scan_kernel(const int* __restrict__ bcnt, int nbuk,
                                   int* __restrict__ boff, int* __restrict__ bcur) {
    int g = blockIdx.x;
    const int* bc = bcnt + g * 1024;
    int* bo = boff + g * 1024;
    int* bu = bcur + g * 1024;
    __shared__ int s[1024];
    int t = threadIdx.x;
    int v = (t < nbuk) ? bc[t] : 0;
    s[t] = v;
    __syncthreads();
    for (int st = 1; st < 1024; st <<= 1) {
        int u = (t >= st) ? s[t - st] : 0;
        __syncthreads();
        s[t] += u;
        __syncthreads();
    }
    if (t < nbuk) { int e = s[t] - v; bo[t] = e; bu[t] = e; }
}

__global__ void bucket_scatter_kernel(const int* __restrict__ e0, const int* __restrict__ e1,
                                      int E, int* __restrict__ bcur,
                                      int* __restrict__ ebuf0, int* __restrict__ ebuf1, int nbuk) {
    int g = blockIdx.y;
    const int* src = g ? e1 : e0;
    const int* dst = src + E;
    int* ebuf = g ? ebuf1 : ebuf0;
    int* bu = bcur + g * 1024;
    __shared__ int hist[1024];
    for (int t = threadIdx.x; t < 1024; t += TPB) hist[t] = 0;
    __syncthreads();
    int base = blockIdx.x * 4096;
    int pk[16], bk[16], rk[16];
#pragma unroll
    for (int k = 0; k < 16; k++) {
        int e = base + k * TPB + (int)threadIdx.x;
        bk[k] = -1;
        if (e < E) {
            int s = src[e], d = dst[e];
            int b = d >> SH;
            bk[k] = b;
            pk[k] = (s << SH) | (d & (BW - 1));
            rk[k] = atomicAdd(&hist[b], 1);
        }
    }
    __syncthreads();
    for (int t = threadIdx.x; t < nbuk; t += TPB) {
        int h = hist[t];
        hist[t] = h ? atomicAdd(&bu[t], h) : 0;
    }
    __syncthreads();
#pragma unroll
    for (int k = 0; k < 16; k++)
        if (bk[k] >= 0) ebuf[hist[bk[k]] + rk[k]] = pk[k];
}

__global__ void bucket_csr_kernel(const int* __restrict__ ebuf0, const int* __restrict__ ebuf1,
                                  const int* __restrict__ boff, const int* __restrict__ bcnt,
                                  int n, int E,
                                  int* __restrict__ off0, int* __restrict__ off1,
                                  float* __restrict__ dinv0, float* __restrict__ dinv1,
                                  int* __restrict__ col0, int* __restrict__ col1) {
    int g = blockIdx.y;
    int b = blockIdx.x;
    const int* ebuf = g ? ebuf1 : ebuf0;
    int* off = g ? off1 : off0;
    float* dinv = g ? dinv1 : dinv0;
    int* col = g ? col1 : col0;
    __shared__ int h[BW], nb[BW], nrank[BW];
    int tid = threadIdx.x;
    if (tid < BW) h[tid] = 0;
    __syncthreads();
    int s = boff[g * 1024 + b], e = s + bcnt[g * 1024 + b];
    for (int i = s + tid; i < e; i += TPB)
        atomicAdd(&h[ebuf[i] & (BW - 1)], 1);
    __syncthreads();
    if (tid < BW) {
        int v = h[tid];
        int x = v;
        for (int d = 1; d < BW; d <<= 1) {
            int u = __shfl_up(x, d, 64);
            if (tid >= d) x += u;
        }
        int base = s + x - v;
        nb[tid] = base;
        nrank[tid] = 0;
        int node = b * BW + tid;
        if (node < n) {
            off[node] = base;
            dinv[node] = rsqrtf((float)v + 1.0f);
        }
        if (node == 0) off[n] = E;
    }
    __syncthreads();
    for (int i = s + tid; i < e; i += TPB) {
        int p = ebuf[i];
        int lo = p & (BW - 1);
        int r = atomicAdd(&nrank[lo], 1);
        col[nb[lo] + r] = p >> SH;
    }
}

template <int CIN, int COUT>
__global__ void matmul_kernel(const float* __restrict__ X0, const float* __restrict__ X1,
                              const float* __restrict__ W,
                              const float* __restrict__ dinv0, const float* __restrict__ dinv1,
                              u16* __restrict__ Y0, u16* __restrict__ Y1, int n) {
    constexpr int CINP = CIN + 8;
    constexpr int NT = COUT / 16;
    constexpr int KT = CIN / 32;
    __shared__ u16 Xs[64 * CINP];
    __shared__ u16 Wt[COUT * CINP];

    int g = blockIdx.y;
    const float* X = g ? X1 : X0;
    const float* dinv = g ? dinv1 : dinv0;
    u16* Y = g ? Y1 : Y0;
    int nb0 = blockIdx.x * 64;

    for (int i = threadIdx.x; i < 64 * (CIN / 4); i += TPB) {
        int nn = i / (CIN / 4), kc = i % (CIN / 4);
        float4 v = make_float4(0.f, 0.f, 0.f, 0.f);
        if (nb0 + nn < n) v = *(const float4*)&X[(size_t)(nb0 + nn) * CIN + 4 * kc];
        ushort4 b;
        b.x = f_to_bf(v.x); b.y = f_to_bf(v.y); b.z = f_to_bf(v.z); b.w = f_to_bf(v.w);
        *(ushort4*)&Xs[nn * CINP + 4 * kc] = b;
    }
    for (int i = threadIdx.x; i < CIN * (COUT / 4); i += TPB) {
        int k = i / (COUT / 4), nc4 = i % (COUT / 4);
        float4 v = *(const float4*)&W[(size_t)k * COUT + 4 * nc4];
        Wt[(4 * nc4 + 0) * CINP + k] = f_to_bf(v.x);
        Wt[(4 * nc4 + 1) * CINP + k] = f_to_bf(v.y);
        Wt[(4 * nc4 + 2) * CINP + k] = f_to_bf(v.z);
        Wt[(4 * nc4 + 3) * CINP + k] = f_to_bf(v.w);
    }
    __syncthreads();

    int lane = threadIdx.x & 63;
    int w = threadIdx.x >> 6;
    int m = lane & 15;
    int quad = lane >> 4;

    f32x4 acc[NT];
#pragma unroll
    for (int t = 0; t < NT; t++) acc[t] = (f32x4){0.f, 0.f, 0.f, 0.f};
#pragma unroll
    for (int kt = 0; kt < KT; kt++) {
        int k0 = kt * 32 + quad * 8;
        bf16x8 a = *(const bf16x8*)&Xs[(w * 16 + m) * CINP + k0];
#pragma unroll
        for (int t = 0; t < NT; t++) {
            bf16x8 b = *(const bf16x8*)&Wt[(t * 16 + m) * CINP + k0];
            acc[t] = __builtin_amdgcn_mfma_f32_16x16x32_bf16(a, b, acc[t], 0, 0, 0);
        }
    }
#pragma unroll
    for (int r = 0; r < 4; r++) {
        int node = nb0 + w * 16 + quad * 4 + r;
        if (node < n) {
            float d = dinv[node];
#pragma unroll
            for (int t = 0; t < NT; t++)
                Y[(size_t)node * COUT + t * 16 + m] = f_to_bf(acc[t][r] * d);
        }
    }
}

template <int C, int SPLIT, bool RELU>
__global__ void agg_kernel(const u16* __restrict__ HW0, const u16* __restrict__ HW1,
                           const int* __restrict__ off0, const int* __restrict__ off1,
                           const int* __restrict__ col0, const int* __restrict__ col1,
                           const float* __restrict__ dinv0, const float* __restrict__ dinv1,
                           const float* __restrict__ bias,
                           float* __restrict__ out0, float* __restrict__ out1, int n) {
    int g = blockIdx.y;
    const u16* HW = g ? HW1 : HW0;
    const int* off = g ? off1 : off0;
    const int* col = g ? col1 : col0;
    const float* dinv = g ? dinv1 : dinv0;
    float* outp = g ? out1 : out0;
    constexpr int CH = C / 4;
    constexpr int TPN = CH * SPLIT;
    int tid = blockIdx.x * blockDim.x + threadIdx.x;
    int node = tid / TPN;
    if (node >= n) return;
    int part = tid % TPN;
    int sp = part / CH;
    int c0 = (part % CH) * 4;
    int s = off[node], e = off[node + 1];
    int len = e - s;
    int chunk = (len + SPLIT - 1) / SPLIT;
    int ps = s + sp * chunk;
    int pe = min(ps + chunk, e);
    float4 r = gather_sum<C>(HW, col, c0, ps, pe);
#pragma unroll
    for (int m = CH; m < TPN; m <<= 1) facc(r, shfl_xor4(r, m, TPN));
    if (sp == 0) {
        float di = dinv[node];
        float4 self = bf4_to_f4(*(const ushort4*)&HW[(size_t)node * C + c0]);
        float4 b4 = *(const float4*)&bias[c0];
        float4 o;
        o.x = di * (r.x + self.x) + b4.x;
        o.y = di * (r.y + self.y) + b4.y;
        o.z = di * (r.z + self.z) + b4.z;
        o.w = di * (r.w + self.w) + b4.w;
        if (RELU) {
            o.x = fmaxf(o.x, 0.f); o.y = fmaxf(o.y, 0.f);
            o.z = fmaxf(o.z, 0.f); o.w = fmaxf(o.w, 0.f);
        }
        *(float4*)&outp[(size_t)node * C + c0] = o;
    }
}

__global__ void colsum_kernel(const float* __restrict__ H0, const float* __restrict__ H1,
                              int n, float* __restrict__ colsum) {
    int g = blockIdx.y;
    const float* H = g ? H1 : H0;
    int c = threadIdx.x % 16;
    int w = (blockIdx.x * blockDim.x + threadIdx.x) / 16;
    int stride = (gridDim.x * blockDim.x) / 16;
    float acc = 0.f;
    for (int node = w; node < n; node += stride) acc += H[(size_t)node * 16 + c];
    __shared__ float sdata[TPB];
    sdata[threadIdx.x] = acc;
    __syncthreads();
    if (threadIdx.x < 16) {
        float s = 0.f;
        for (int t = threadIdx.x; t < TPB; t += 16) s += sdata[t];
        atomicAdd(&colsum[g * 16 + threadIdx.x], s);
    }
}

__global__ void cvec_kernel(const float* __restrict__ colsum, const float* __restrict__ Wa,
                            float n_inv, float* __restrict__ cvec) {
    int g = blockIdx.x;
    int j = threadIdx.x;
    if (j < 16) {
        const float* cs = colsum + g * 16;
        float acc = 0.f;
        for (int i = 0; i < 16; i++) acc += (cs[i] * n_inv) * Wa[i * 16 + j];
        cvec[g * 16 + j] = tanhf(acc);
    }
}

__global__ void pool_kernel(const float* __restrict__ H0, const float* __restrict__ H1, int n,
                            const float* __restrict__ cvec, float* __restrict__ rep) {
    int g = blockIdx.y;
    const float* H = g ? H1 : H0;
    int c = threadIdx.x % 16;
    float cv = cvec[g * 16 + c];
    int w = (blockIdx.x * blockDim.x + threadIdx.x) / 16;
    int stride = (gridDim.x * blockDim.x) / 16;
    float acc = 0.f;
    for (int node = w; node < n; node += stride) {
        float x = H[(size_t)node * 16 + c];
        float p = x * cv;
        p += __shfl_xor(p, 1, 16);
        p += __shfl_xor(p, 2, 16);
        p += __shfl_xor(p, 4, 16);
        p += __shfl_xor(p, 8, 16);
        float s = 1.f / (1.f + __expf(-p));
        acc += s * x;
    }
    __shared__ float sdata[TPB];
    sdata[threadIdx.x] = acc;
    __syncthreads();
    if (threadIdx.x < 16) {
        float s = 0.f;
        for (int t = threadIdx.x; t < TPB; t += 16) s += sdata[t];
        atomicAdd(&rep[g * 16 + threadIdx.x], s);
    }
}

__global__ void final_kernel(const float* __restrict__ rep,
                             const float* __restrict__ Wt, const float* __restrict__ Wb,
                             const float* __restrict__ bt, const float* __restrict__ Wfc,
                             const float* __restrict__ bfc, const float* __restrict__ Wsc,
                             const float* __restrict__ bsc, float* __restrict__ out) {
    const float* e1 = rep;
    const float* e2 = rep + 16;
    __shared__ float scores[16], tvec[16], se1[16], se2[16];
    int t = threadIdx.x;
    if (t < 16) { se1[t] = e1[t]; se2[t] = e2[t]; }
    __syncthreads();
    if (t < 16) {
        float bil = 0.f;
        for (int i = 0; i < 16; i++) {
            float a = se1[i];
            for (int j = 0; j < 16; j++) bil += a * se2[j] * Wt[(i * 16 + j) * 16 + t];
        }
        float blk = 0.f;
        for (int m = 0; m < 16; m++)
            blk += Wb[t * 32 + m] * se1[m] + Wb[t * 32 + 16 + m] * se2[m];
        scores[t] = fmaxf(bil + blk + bt[t], 0.f);
    }
    __syncthreads();
    if (t < 16) {
        float acc = bfc[t];
        for (int k = 0; k < 16; k++) acc += scores[k] * Wfc[k * 16 + t];
        tvec[t] = tanhf(acc);
    }
    __syncthreads();
    if (t == 0) {
        float acc = bsc[0];
        for (int j = 0; j < 16; j++) acc += tvec[j] * Wsc[j];
        out[0] = 1.f / (1.f + __expf(-acc));
    }
}

// ---------------- launcher ----------------

extern "C" void kernel_launch(void* const* d_in, const int* in_sizes, int n_in,
                              void* d_out, int out_size, void* d_ws, size_t ws_size,
                              hipStream_t stream) {
    const float* X1 = (const float*)d_in[0];
    const float* X2 = (const float*)d_in[1];
    const int* edges1 = (const int*)d_in[2];
    const int* edges2 = (const int*)d_in[3];
    const float* W1 = (const float*)d_in[4];
    const float* b1 = (const float*)d_in[5];
    const float* W2 = (const float*)d_in[6];
    const float* b2 = (const float*)d_in[7];
    const float* W3 = (const float*)d_in[8];
    const float* b3 = (const float*)d_in[9];
    const float* Wa = (const float*)d_in[10];
    const float* Wt = (const float*)d_in[11];
    const float* Wb = (const float*)d_in[12];
    const float* bt = (const float*)d_in[13];
    const float* Wfc = (const float*)d_in[14];
    const float* bfc = (const float*)d_in[15];
    const float* Wsc = (const float*)d_in[16];
    const float* bsc = (const float*)d_in[17];
    float* out = (float*)d_out;

    const int N = in_sizes[0] / 96;
    const int E = in_sizes[2] / 2;
    const int NBUK = (N + BW - 1) / BW;

    char* ws = (char*)d_ws;
    size_t o = 0;
    auto alloc = [&](size_t bytes) {
        void* p = ws + o;
        o += (bytes + 255) & ~(size_t)255;
        return p;
    };
    int* bcnt = (int*)alloc((size_t)2 * 1024 * 4);
    float* smallv = (float*)alloc(96 * 4);  // fallback: colsum[32] cvec[32] rep[32]
    int* boff = (int*)alloc((size_t)2 * 1024 * 4);
    int* bcur = (int*)alloc((size_t)2 * 1024 * 4);
    float* partial = (float*)alloc((size_t)1024 * 16 * 4);
    float* cvecArr = (float*)alloc(32 * 4);
    int* off0 = (int*)alloc((size_t)(N + 1) * 4);
    int* off1 = (int*)alloc((size_t)(N + 1) * 4);
    int* col0 = (int*)alloc((size_t)E * 4);
    int* col1 = (int*)alloc((size_t)E * 4);
    float* dinv0 = (float*)alloc((size_t)N * 4);
    float* dinv1 = (float*)alloc((size_t)N * 4);
    int* ebuf0 = (int*)alloc((size_t)E * 4);
    int* ebuf1 = (int*)alloc((size_t)E * 4);
    u16* hwb0 = (u16*)alloc((size_t)N * 64 * 2);
    u16* hwb1 = (u16*)alloc((size_t)N * 64 * 2);
    float* bufB0 = (float*)alloc((size_t)N * 64 * 4);
    float* bufB1 = (float*)alloc((size_t)N * 64 * 4);

    const int gB1 = (E + 8191) / 8192;
    const int gB2 = (E + 4095) / 4096;
    const int g16 = ((size_t)N * 16 + TPB - 1) / TPB;
    const int gMM = (N + 63) / 64;

    MegaArgs A;
    A.X1 = X1; A.X2 = X2; A.e1 = edges1; A.e2 = edges2;
    A.W1 = W1; A.b1 = b1; A.W2 = W2; A.b2 = b2; A.W3 = W3; A.b3 = b3;
    A.Wa = Wa; A.Wten = Wt; A.Wb = Wb; A.bt = bt;
    A.Wfc = Wfc; A.bfc = bfc; A.Wsc = Wsc; A.bsc = bsc;
    A.out = out;
    A.N = N; A.E = E; A.NBUK = NBUK; A.gMM = gMM; A.g16 = g16; A.gB1 = gB1; A.gB2 = gB2;
    A.bcnt = bcnt; A.boff = boff; A.bcur = bcur;
    A.off0 = off0; A.off1 = off1; A.col0 = col0; A.col1 = col1;
    A.ebuf0 = ebuf0; A.ebuf1 = ebuf1;
    A.dinv0 = dinv0; A.dinv1 = dinv1;
    A.hwb0 = hwb0; A.hwb1 = hwb1;
    A.bufB0 = bufB0; A.bufB1 = bufB1;
    A.partial = partial; A.cvecArr = cvecArr;

    int maxB = 2;
    if (hipOccupancyMaxActiveBlocksPerMultiprocessor(&maxB, (const void*)mega_kernel, TPB, 0)
        != hipSuccess || maxB < 1) maxB = 1;
    int G = maxB * 256;
    if (G > 1024) G = 1024;
    if (G < 256) G = 256;

    void* params[] = { (void*)&A };
    hipError_t err = hipLaunchCooperativeKernel((void*)mega_kernel, dim3(G), dim3(TPB),
                                                params, 0, stream);
    if (err == hipSuccess) return;

    // -------- fallback: proven 15-dispatch pipeline --------
    hipMemsetAsync(bcnt, 0, (size_t)2 * 1024 * 4, stream);
    hipMemsetAsync(smallv, 0, 96 * 4, stream);

    bucket_count_kernel<<<dim3(gB1, 2), TPB, 0, stream>>>(edges1 + E, edges2 + E, E, bcnt, NBUK);
    bucket_scan_kernel<<<2, 1024, 0, stream>>>(bcnt, NBUK, boff, bcur);
    bucket_scatter_kernel<<<dim3(gB2, 2), TPB, 0, stream>>>(edges1, edges2, E, bcur, ebuf0, ebuf1, NBUK);
    bucket_csr_kernel<<<dim3(NBUK, 2), TPB, 0, stream>>>(ebuf0, ebuf1, boff, bcnt, N, E,
                                                         off0, off1, dinv0, dinv1, col0, col1);

    matmul_kernel<96, 64><<<dim3(gMM, 2), TPB, 0, stream>>>(X1, X2, W1, dinv0, dinv1, hwb0, hwb1, N);
    agg_kernel<64, 1, true><<<dim3(g16, 2), TPB, 0, stream>>>(
        hwb0, hwb1, off0, off1, col0, col1, dinv0, dinv1, b1, bufB0, bufB1, N);
    matmul_kernel<64, 32><<<dim3(gMM, 2), TPB, 0, stream>>>(bufB0, bufB1, W2, dinv0, dinv1, hwb0, hwb1, N);
    agg_kernel<32, 2, true><<<dim3(g16, 2), TPB, 0, stream>>>(
        hwb0, hwb1, off0, off1, col0, col1, dinv0, dinv1, b2, bufB0, bufB1, N);
    matmul_kernel<32, 16><<<dim3(gMM, 2), TPB, 0, stream>>>(bufB0, bufB1, W3, dinv0, dinv1, hwb0, hwb1, N);
    agg_kernel<16, 4, false><<<dim3(g16, 2), TPB, 0, stream>>>(
        hwb0, hwb1, off0, off1, col0, col1, dinv0, dinv1, b3, bufB0, bufB1, N);

    colsum_kernel<<<dim3(64, 2), TPB, 0, stream>>>(bufB0, bufB1, N, smallv);
    cvec_kernel<<<2, 64, 0, stream>>>(smallv, Wa, 1.0f / (float)N, smallv + 32);
    pool_kernel<<<dim3(64, 2), TPB, 0, stream>>>(bufB0, bufB1, N, smallv + 32, smallv + 64);
    final_kernel<<<1, 64, 0, stream>>>(smallv + 64, Wt, Wb, bt, Wfc, bfc, Wsc, bsc, out);
}

// Round 12
// 341.372 us; speedup vs baseline: 4.8460x; 4.8460x over previous
//
#include <hip/hip_runtime.h>
#include <hip/hip_bf16.h>

#define TPB 256
#define SH 6
#define BW 64  // nodes per bucket = 1<<SH; NBUK must be <= 1024 (N <= 65536)

typedef unsigned short u16;
typedef __attribute__((ext_vector_type(8))) __bf16 bf16x8;  // MFMA A/B frag (4 VGPRs)
typedef __attribute__((ext_vector_type(4))) float f32x4;    // MFMA C/D frag

// bf16 helpers: payload stored as bf16 (halves gather BW), accumulate in fp32.
__device__ __forceinline__ u16 f_to_bf(float f) {
    unsigned u = __float_as_uint(f);
    return (u16)((u + 0x7fff + ((u >> 16) & 1)) >> 16);  // RNE
}
__device__ __forceinline__ float4 bf4_to_f4(ushort4 v) {
    float4 r;
    r.x = __uint_as_float((unsigned)v.x << 16);
    r.y = __uint_as_float((unsigned)v.y << 16);
    r.z = __uint_as_float((unsigned)v.z << 16);
    r.w = __uint_as_float((unsigned)v.w << 16);
    return r;
}
__device__ __forceinline__ void facc(float4& a, float4 v) {
    a.x += v.x; a.y += v.y; a.z += v.z; a.w += v.w;
}
__device__ __forceinline__ float4 shfl_xor4(float4 v, int mask, int width) {
    v.x = __shfl_xor(v.x, mask, width);
    v.y = __shfl_xor(v.y, mask, width);
    v.z = __shfl_xor(v.z, mask, width);
    v.w = __shfl_xor(v.w, mask, width);
    return v;
}

template <int C>
__device__ __forceinline__ float4 gather_sum(const u16* __restrict__ HW,
                                             const int* __restrict__ col,
                                             int c0, int ps, int pe) {
    float4 a0 = make_float4(0.f, 0.f, 0.f, 0.f);
    float4 a1 = a0, a2 = a0, a3 = a0;
    int p = ps;
    for (; p + 4 <= pe; p += 4) {
        int j0 = col[p], j1 = col[p + 1], j2 = col[p + 2], j3 = col[p + 3];
        facc(a0, bf4_to_f4(*(const ushort4*)&HW[(size_t)j0 * C + c0]));
        facc(a1, bf4_to_f4(*(const ushort4*)&HW[(size_t)j1 * C + c0]));
        facc(a2, bf4_to_f4(*(const ushort4*)&HW[(size_t)j2 * C + c0]));
        facc(a3, bf4_to_f4(*(const ushort4*)&HW[(size_t)j3 * C + c0]));
    }
    for (; p < pe; p++) {
        int j = col[p];
        facc(a0, bf4_to_f4(*(const ushort4*)&HW[(size_t)j * C + c0]));
    }
    facc(a0, a1); facc(a2, a3); facc(a0, a2);
    return a0;
}

// ---------------- bucketed CSR build ----------------

__global__ void bucket_count_kernel(const int* __restrict__ dst0, const int* __restrict__ dst1,
                                    int E, int* __restrict__ bcnt, int nbuk) {
    const int* dst = blockIdx.y ? dst1 : dst0;
    int* bc = bcnt + blockIdx.y * 1024;
    __shared__ int hist[1024];
    for (int t = threadIdx.x; t < 1024; t += TPB) hist[t] = 0;
    __syncthreads();
    int base = blockIdx.x * 8192;
    int end = min(base + 8192, E);
    for (int e = base + (int)threadIdx.x; e < end; e += TPB)
        atomicAdd(&hist[dst[e] >> SH], 1);
    __syncthreads();
    for (int t = threadIdx.x; t < nbuk; t += TPB) {
        int h = hist[t];
        if (h) atomicAdd(&bc[t], h);
    }
}

__global__ void bucket_scan_kernel(const int* __restrict__ bcnt, int nbuk,
                                   int* __restrict__ boff, int* __restrict__ bcur) {
    int g = blockIdx.x;
    const int* bc = bcnt + g * 1024;
    int* bo = boff + g * 1024;
    int* bu = bcur + g * 1024;
    __shared__ int s[1024];
    int t = threadIdx.x;
    int v = (t < nbuk) ? bc[t] : 0;
    s[t] = v;
    __syncthreads();
    for (int st = 1; st < 1024; st <<= 1) {
        int u = (t >= st) ? s[t - st] : 0;
        __syncthreads();
        s[t] += u;
        __syncthreads();
    }
    if (t < nbuk) { int e = s[t] - v; bo[t] = e; bu[t] = e; }
}

__global__ void bucket_scatter_kernel(const int* __restrict__ e0, const int* __restrict__ e1,
                                      int E, int* __restrict__ bcur,
                                      int* __restrict__ ebuf0, int* __restrict__ ebuf1, int nbuk) {
    int g = blockIdx.y;
    const int* src = g ? e1 : e0;
    const int* dst = src + E;
    int* ebuf = g ? ebuf1 : ebuf0;
    int* bu = bcur + g * 1024;
    __shared__ int hist[1024];
    for (int t = threadIdx.x; t < 1024; t += TPB) hist[t] = 0;
    __syncthreads();
    int base = blockIdx.x * 4096;
    int pk[16], bk[16], rk[16];
#pragma unroll
    for (int k = 0; k < 16; k++) {
        int e = base + k * TPB + (int)threadIdx.x;
        bk[k] = -1;
        if (e < E) {
            int s = src[e], d = dst[e];
            int b = d >> SH;
            bk[k] = b;
            pk[k] = (s << SH) | (d & (BW - 1));
            rk[k] = atomicAdd(&hist[b], 1);
        }
    }
    __syncthreads();
    for (int t = threadIdx.x; t < nbuk; t += TPB) {
        int h = hist[t];
        hist[t] = h ? atomicAdd(&bu[t], h) : 0;
    }
    __syncthreads();
#pragma unroll
    for (int k = 0; k < 16; k++)
        if (bk[k] >= 0) ebuf[hist[bk[k]] + rk[k]] = pk[k];
}

// Fused: per-bucket histogram -> local scan -> off/dinv -> fill col.
__global__ void bucket_csr_kernel(const int* __restrict__ ebuf0, const int* __restrict__ ebuf1,
                                  const int* __restrict__ boff, const int* __restrict__ bcnt,
                                  int n, int E,
                                  int* __restrict__ off0, int* __restrict__ off1,
                                  float* __restrict__ dinv0, float* __restrict__ dinv1,
                                  int* __restrict__ col0, int* __restrict__ col1) {
    int g = blockIdx.y;
    int b = blockIdx.x;
    const int* ebuf = g ? ebuf1 : ebuf0;
    int* off = g ? off1 : off0;
    float* dinv = g ? dinv1 : dinv0;
    int* col = g ? col1 : col0;
    __shared__ int h[BW], nb[BW], nrank[BW];
    int tid = threadIdx.x;
    if (tid < BW) h[tid] = 0;
    __syncthreads();
    int s = boff[g * 1024 + b], e = s + bcnt[g * 1024 + b];
    for (int i = s + tid; i < e; i += TPB)
        atomicAdd(&h[ebuf[i] & (BW - 1)], 1);
    __syncthreads();
    if (tid < BW) {
        int v = h[tid];
        int x = v;
        for (int d = 1; d < BW; d <<= 1) {
            int u = __shfl_up(x, d, 64);
            if (tid >= d) x += u;
        }
        int base = s + x - v;  // exclusive
        nb[tid] = base;
        nrank[tid] = 0;
        int node = b * BW + tid;
        if (node < n) {
            off[node] = base;
            dinv[node] = rsqrtf((float)v + 1.0f);
        }
        if (node == 0) off[n] = E;
    }
    __syncthreads();
    for (int i = s + tid; i < e; i += TPB) {
        int p = ebuf[i];
        int lo = p & (BW - 1);
        int r = atomicAdd(&nrank[lo], 1);
        col[nb[lo] + r] = p >> SH;
    }
}

// ---------------- dense matmul via MFMA: Y = bf16( dinv[n] * (X @ W) ) ----------

template <int CIN, int COUT>
__global__ void matmul_kernel(const float* __restrict__ X0, const float* __restrict__ X1,
                              const float* __restrict__ W,
                              const float* __restrict__ dinv0, const float* __restrict__ dinv1,
                              u16* __restrict__ Y0, u16* __restrict__ Y1, int n) {
    constexpr int CINP = CIN + 8;
    constexpr int NT = COUT / 16;
    constexpr int KT = CIN / 32;
    __shared__ u16 Xs[64 * CINP];
    __shared__ u16 Wt[COUT * CINP];

    int g = blockIdx.y;
    const float* X = g ? X1 : X0;
    const float* dinv = g ? dinv1 : dinv0;
    u16* Y = g ? Y1 : Y0;
    int nb0 = blockIdx.x * 64;

    for (int i = threadIdx.x; i < 64 * (CIN / 4); i += TPB) {
        int nn = i / (CIN / 4), kc = i % (CIN / 4);
        float4 v = make_float4(0.f, 0.f, 0.f, 0.f);
        if (nb0 + nn < n) v = *(const float4*)&X[(size_t)(nb0 + nn) * CIN + 4 * kc];
        ushort4 b;
        b.x = f_to_bf(v.x); b.y = f_to_bf(v.y); b.z = f_to_bf(v.z); b.w = f_to_bf(v.w);
        *(ushort4*)&Xs[nn * CINP + 4 * kc] = b;
    }
    for (int i = threadIdx.x; i < CIN * (COUT / 4); i += TPB) {
        int k = i / (COUT / 4), nc4 = i % (COUT / 4);
        float4 v = *(const float4*)&W[(size_t)k * COUT + 4 * nc4];
        Wt[(4 * nc4 + 0) * CINP + k] = f_to_bf(v.x);
        Wt[(4 * nc4 + 1) * CINP + k] = f_to_bf(v.y);
        Wt[(4 * nc4 + 2) * CINP + k] = f_to_bf(v.z);
        Wt[(4 * nc4 + 3) * CINP + k] = f_to_bf(v.w);
    }
    __syncthreads();

    int lane = threadIdx.x & 63;
    int w = threadIdx.x >> 6;
    int m = lane & 15;
    int quad = lane >> 4;

    f32x4 acc[NT];
#pragma unroll
    for (int t = 0; t < NT; t++) acc[t] = (f32x4){0.f, 0.f, 0.f, 0.f};
#pragma unroll
    for (int kt = 0; kt < KT; kt++) {
        int k0 = kt * 32 + quad * 8;
        bf16x8 a = *(const bf16x8*)&Xs[(w * 16 + m) * CINP + k0];
#pragma unroll
        for (int t = 0; t < NT; t++) {
            bf16x8 b = *(const bf16x8*)&Wt[(t * 16 + m) * CINP + k0];
            acc[t] = __builtin_amdgcn_mfma_f32_16x16x32_bf16(a, b, acc[t], 0, 0, 0);
        }
    }
#pragma unroll
    for (int r = 0; r < 4; r++) {
        int node = nb0 + w * 16 + quad * 4 + r;
        if (node < n) {
            float d = dinv[node];
#pragma unroll
            for (int t = 0; t < NT; t++)
                Y[(size_t)node * COUT + t * 16 + m] = f_to_bf(acc[t][r] * d);
        }
    }
}

// ---------------- GCN aggregation (gather over CSR-by-dst, bf16 payload) -------------

template <int C, int SPLIT, bool RELU>
__global__ void agg_kernel(const u16* __restrict__ HW0, const u16* __restrict__ HW1,
                           const int* __restrict__ off0, const int* __restrict__ off1,
                           const int* __restrict__ col0, const int* __restrict__ col1,
                           const float* __restrict__ dinv0, const float* __restrict__ dinv1,
                           const float* __restrict__ bias,
                           float* __restrict__ out0, float* __restrict__ out1, int n) {
    int g = blockIdx.y;
    const u16* HW = g ? HW1 : HW0;
    const int* off = g ? off1 : off0;
    const int* col = g ? col1 : col0;
    const float* dinv = g ? dinv1 : dinv0;
    float* outp = g ? out1 : out0;
    constexpr int CH = C / 4;
    constexpr int TPN = CH * SPLIT;
    int tid = blockIdx.x * blockDim.x + threadIdx.x;
    int node = tid / TPN;
    if (node >= n) return;
    int part = tid % TPN;
    int sp = part / CH;
    int c0 = (part % CH) * 4;
    int s = off[node], e = off[node + 1];
    int len = e - s;
    int chunk = (len + SPLIT - 1) / SPLIT;
    int ps = s + sp * chunk;
    int pe = min(ps + chunk, e);
    float4 r = gather_sum<C>(HW, col, c0, ps, pe);
#pragma unroll
    for (int m = CH; m < TPN; m <<= 1) facc(r, shfl_xor4(r, m, TPN));
    if (sp == 0) {
        float di = dinv[node];
        float4 self = bf4_to_f4(*(const ushort4*)&HW[(size_t)node * C + c0]);
        float4 b4 = *(const float4*)&bias[c0];
        float4 o;
        o.x = di * (r.x + self.x) + b4.x;
        o.y = di * (r.y + self.y) + b4.y;
        o.z = di * (r.z + self.z) + b4.z;
        o.w = di * (r.w + self.w) + b4.w;
        if (RELU) {
            o.x = fmaxf(o.x, 0.f); o.y = fmaxf(o.y, 0.f);
            o.z = fmaxf(o.z, 0.f); o.w = fmaxf(o.w, 0.f);
        }
        *(float4*)&outp[(size_t)node * C + c0] = o;
    }
}

// Layer-3 aggregation (C=16, SPLIT=4) + per-block colsum partials (NO atomics).
__global__ void agg16_kernel(const u16* __restrict__ HW0, const u16* __restrict__ HW1,
                             const int* __restrict__ off0, const int* __restrict__ off1,
                             const int* __restrict__ col0, const int* __restrict__ col1,
                             const float* __restrict__ dinv0, const float* __restrict__ dinv1,
                             const float* __restrict__ bias,
                             float* __restrict__ out0, float* __restrict__ out1,
                             float* __restrict__ pcol, int n) {
    int g = blockIdx.y;
    const u16* HW = g ? HW1 : HW0;
    const int* off = g ? off1 : off0;
    const int* col = g ? col1 : col0;
    const float* dinv = g ? dinv1 : dinv0;
    float* outp = g ? out1 : out0;
    int tid = blockIdx.x * blockDim.x + threadIdx.x;
    int node = tid / 16;
    int part = tid % 16;
    int sp = part / 4;
    int c0 = (part % 4) * 4;
    float4 o = make_float4(0.f, 0.f, 0.f, 0.f);
    if (node < n) {
        int s = off[node], e = off[node + 1];
        int len = e - s;
        int chunk = (len + 3) / 4;
        int ps = s + sp * chunk;
        int pe = min(ps + chunk, e);
        float4 r = gather_sum<16>(HW, col, c0, ps, pe);
        facc(r, shfl_xor4(r, 4, 16));
        facc(r, shfl_xor4(r, 8, 16));
        if (sp == 0) {
            float di = dinv[node];
            float4 self = bf4_to_f4(*(const ushort4*)&HW[(size_t)node * 16 + c0]);
            float4 b4 = *(const float4*)&bias[c0];
            o.x = di * (r.x + self.x) + b4.x;
            o.y = di * (r.y + self.y) + b4.y;
            o.z = di * (r.z + self.z) + b4.z;
            o.w = di * (r.w + self.w) + b4.w;
            *(float4*)&outp[(size_t)node * 16 + c0] = o;
        }
    }
    // per-block colsum partial (only sp==0 lanes hold data)
    __shared__ float4 sd[TPB];
    sd[threadIdx.x] = (node < n && sp == 0) ? o : make_float4(0.f, 0.f, 0.f, 0.f);
    __syncthreads();
    if (threadIdx.x < 64) {
        float4 a = sd[threadIdx.x];
        facc(a, sd[threadIdx.x + 64]);
        facc(a, sd[threadIdx.x + 128]);
        facc(a, sd[threadIdx.x + 192]);
        sd[threadIdx.x] = a;
    }
    __syncthreads();
    if (threadIdx.x < 16) {
        float4 a = sd[threadIdx.x];
        facc(a, sd[threadIdx.x + 16]);
        facc(a, sd[threadIdx.x + 32]);
        facc(a, sd[threadIdx.x + 48]);
        sd[threadIdx.x] = a;
    }
    __syncthreads();
    if (threadIdx.x < 4)
        *(float4*)&pcol[((size_t)g * gridDim.x + blockIdx.x) * 16 + threadIdx.x * 4] = sd[threadIdx.x];
}

// ---------------- attention pooling ----------------
// Each block redundantly computes cvec from pcol partials (deterministic, L2-resident),
// then pools its node stripe and writes a per-block partial (NO atomics).

__global__ void pool_kernel(const float* __restrict__ H0, const float* __restrict__ H1, int n,
                            const float* __restrict__ pcol, int nb16, float n_inv,
                            const float* __restrict__ Wa, float* __restrict__ ppool) {
    int g = blockIdx.y;
    const float* H = g ? H1 : H0;
    __shared__ float sdata[TPB];
    __shared__ float cs[16];
    __shared__ float cvecS[16];
    int c = threadIdx.x & 15;
    // redundant cvec: reduce colsum partials
    {
        int chunk = threadIdx.x >> 4;
        float s = 0.f;
        for (int b = chunk; b < nb16; b += 16) s += pcol[((size_t)g * nb16 + b) * 16 + c];
        sdata[threadIdx.x] = s;
        __syncthreads();
        if (threadIdx.x < 16) {
            float t = 0.f;
            for (int k = threadIdx.x; k < TPB; k += 16) t += sdata[k];
            cs[threadIdx.x] = t * n_inv;
        }
        __syncthreads();
        if (threadIdx.x < 16) {
            float acc = 0.f;
            for (int i = 0; i < 16; i++) acc += cs[i] * Wa[i * 16 + threadIdx.x];
            cvecS[threadIdx.x] = tanhf(acc);
        }
        __syncthreads();
    }
    float cv = cvecS[c];
    int w = (blockIdx.x * blockDim.x + threadIdx.x) / 16;
    int stride = (gridDim.x * blockDim.x) / 16;
    float acc = 0.f;
    for (int node = w; node < n; node += stride) {
        float x = H[(size_t)node * 16 + c];
        float p = x * cv;
        p += __shfl_xor(p, 1, 16);
        p += __shfl_xor(p, 2, 16);
        p += __shfl_xor(p, 4, 16);
        p += __shfl_xor(p, 8, 16);
        float s = 1.f / (1.f + __expf(-p));
        acc += s * x;
    }
    __syncthreads();
    sdata[threadIdx.x] = acc;
    __syncthreads();
    if (threadIdx.x < 16) {
        float s = 0.f;
        for (int t = threadIdx.x; t < TPB; t += 16) s += sdata[t];
        ppool[((size_t)g * gridDim.x + blockIdx.x) * 16 + threadIdx.x] = s;
    }
}

// ---------------- final: reduce pool partials + tensor-network scoring ----------------

__global__ void final_kernel(const float* __restrict__ ppool, int nbp,
                             const float* __restrict__ Wt, const float* __restrict__ Wb,
                             const float* __restrict__ bt, const float* __restrict__ Wfc,
                             const float* __restrict__ bfc, const float* __restrict__ Wsc,
                             const float* __restrict__ bsc, float* __restrict__ out) {
    __shared__ float rep[32], scores[16], tvec[16];
    int t = threadIdx.x;
    if (t < 32) {
        int g = t >> 4, c = t & 15;
        float s = 0.f;
        for (int b = 0; b < nbp; b++) s += ppool[((size_t)g * nbp + b) * 16 + c];
        rep[t] = s;
    }
    __syncthreads();
    if (t < 16) {
        float bil = 0.f;
        for (int i = 0; i < 16; i++) {
            float a = rep[i];
            for (int j = 0; j < 16; j++) bil += a * rep[16 + j] * Wt[(i * 16 + j) * 16 + t];
        }
        float blk = 0.f;
        for (int m = 0; m < 16; m++)
            blk += Wb[t * 32 + m] * rep[m] + Wb[t * 32 + 16 + m] * rep[16 + m];
        scores[t] = fmaxf(bil + blk + bt[t], 0.f);
    }
    __syncthreads();
    if (t < 16) {
        float acc = bfc[t];
        for (int k = 0; k < 16; k++) acc += scores[k] * Wfc[k * 16 + t];
        tvec[t] = tanhf(acc);
    }
    __syncthreads();
    if (t == 0) {
        float acc = bsc[0];
        for (int j = 0; j < 16; j++) acc += tvec[j] * Wsc[j];
        out[0] = 1.f / (1.f + __expf(-acc));
    }
}

// ---------------- launcher ----------------

extern "C" void kernel_launch(void* const* d_in, const int* in_sizes, int n_in,
                              void* d_out, int out_size, void* d_ws, size_t ws_size,
                              hipStream_t stream) {
    const float* X1 = (const float*)d_in[0];
    const float* X2 = (const float*)d_in[1];
    const int* edges1 = (const int*)d_in[2];
    const int* edges2 = (const int*)d_in[3];
    const float* W1 = (const float*)d_in[4];
    const float* b1 = (const float*)d_in[5];
    const float* W2 = (const float*)d_in[6];
    const float* b2 = (const float*)d_in[7];
    const float* W3 = (const float*)d_in[8];
    const float* b3 = (const float*)d_in[9];
    const float* Wa = (const float*)d_in[10];
    const float* Wt = (const float*)d_in[11];
    const float* Wb = (const float*)d_in[12];
    const float* bt = (const float*)d_in[13];
    const float* Wfc = (const float*)d_in[14];
    const float* bfc = (const float*)d_in[15];
    const float* Wsc = (const float*)d_in[16];
    const float* bsc = (const float*)d_in[17];
    float* out = (float*)d_out;

    const int N = in_sizes[0] / 96;
    const int E = in_sizes[2] / 2;
    const int NBUK = (N + BW - 1) / BW;  // buckets (must be <= 1024)

    char* ws = (char*)d_ws;
    size_t o = 0;
    auto alloc = [&](size_t bytes) {
        void* p = ws + o;
        o += (bytes + 255) & ~(size_t)255;
        return p;
    };
    int* bcnt = (int*)alloc((size_t)2 * 1024 * 4);
    int* boff = (int*)alloc((size_t)2 * 1024 * 4);
    int* bcur = (int*)alloc((size_t)2 * 1024 * 4);
    int* off0 = (int*)alloc((size_t)(N + 1) * 4);
    int* off1 = (int*)alloc((size_t)(N + 1) * 4);
    int* col0 = (int*)alloc((size_t)E * 4);
    int* col1 = (int*)alloc((size_t)E * 4);
    float* dinv0 = (float*)alloc((size_t)N * 4);
    float* dinv1 = (float*)alloc((size_t)N * 4);
    int* ebuf0 = (int*)alloc((size_t)E * 4);
    int* ebuf1 = (int*)alloc((size_t)E * 4);
    u16* hwb0 = (u16*)alloc((size_t)N * 64 * 2);   // bf16 gather payload
    u16* hwb1 = (u16*)alloc((size_t)N * 64 * 2);
    float* bufB0 = (float*)alloc((size_t)N * 64 * 4);  // fp32 agg outputs
    float* bufB1 = (float*)alloc((size_t)N * 64 * 4);

    const int gB1 = (E + 8191) / 8192;
    const int gB2 = (E + 4095) / 4096;
    const int g16 = ((size_t)N * 16 + TPB - 1) / TPB;  // all aggs run 16 threads/node
    const int gMM = (N + 63) / 64;                     // MFMA matmul: 64 nodes/block
    const int gPool = 64;                              // pool blocks per graph

    float* pcol = (float*)alloc((size_t)2 * g16 * 16 * 4);   // agg16 colsum partials
    float* ppool = (float*)alloc((size_t)2 * gPool * 16 * 4);

    hipMemsetAsync(bcnt, 0, (size_t)2 * 1024 * 4, stream);

    // bucketed CSR build (both graphs per dispatch)
    bucket_count_kernel<<<dim3(gB1, 2), TPB, 0, stream>>>(edges1 + E, edges2 + E, E, bcnt, NBUK);
    bucket_scan_kernel<<<2, 1024, 0, stream>>>(bcnt, NBUK, boff, bcur);
    bucket_scatter_kernel<<<dim3(gB2, 2), TPB, 0, stream>>>(edges1, edges2, E, bcur, ebuf0, ebuf1, NBUK);
    bucket_csr_kernel<<<dim3(NBUK, 2), TPB, 0, stream>>>(ebuf0, ebuf1, boff, bcnt, N, E,
                                                         off0, off1, dinv0, dinv1, col0, col1);

    // layer 1: 96 -> 64 (MFMA), agg + relu (SPLIT=1: 16 threads/node)
    matmul_kernel<96, 64><<<dim3(gMM, 2), TPB, 0, stream>>>(X1, X2, W1, dinv0, dinv1, hwb0, hwb1, N);
    agg_kernel<64, 1, true><<<dim3(g16, 2), TPB, 0, stream>>>(
        hwb0, hwb1, off0, off1, col0, col1, dinv0, dinv1, b1, bufB0, bufB1, N);
    // layer 2: 64 -> 32 (MFMA), agg + relu (SPLIT=2)
    matmul_kernel<64, 32><<<dim3(gMM, 2), TPB, 0, stream>>>(bufB0, bufB1, W2, dinv0, dinv1, hwb0, hwb1, N);
    agg_kernel<32, 2, true><<<dim3(g16, 2), TPB, 0, stream>>>(
        hwb0, hwb1, off0, off1, col0, col1, dinv0, dinv1, b2, bufB0, bufB1, N);
    // layer 3: 32 -> 16 (MFMA), agg + colsum partials (SPLIT=4)
    matmul_kernel<32, 16><<<dim3(gMM, 2), TPB, 0, stream>>>(bufB0, bufB1, W3, dinv0, dinv1, hwb0, hwb1, N);
    agg16_kernel<<<dim3(g16, 2), TPB, 0, stream>>>(
        hwb0, hwb1, off0, off1, col0, col1, dinv0, dinv1, b3, bufB0, bufB1, pcol, N);

    // attention pooling: per-block redundant cvec + pool partials; final reduces + scores
    pool_kernel<<<dim3(gPool, 2), TPB, 0, stream>>>(bufB0, bufB1, N, pcol, g16,
                                                    1.0f / (float)N, Wa, ppool);
    final_kernel<<<1, 256, 0, stream>>>(ppool, gPool, Wt, Wb, bt, Wfc, bfc, Wsc, bsc, out);
}

// Round 13
// 324.297 us; speedup vs baseline: 5.1012x; 1.0527x over previous
//
#include <hip/hip_runtime.h>
#include <hip/hip_bf16.h>

#define TPB 256
#define SH 6
#define BW 64  // nodes per bucket = 1<<SH; NBUK must be <= 1024 (N <= 65536)

typedef unsigned short u16;
typedef __attribute__((ext_vector_type(8))) __bf16 bf16x8;  // MFMA A/B frag (4 VGPRs)
typedef __attribute__((ext_vector_type(4))) float f32x4;    // MFMA C/D frag

// bf16 helpers: payload stored as bf16 (halves gather BW), accumulate in fp32.
__device__ __forceinline__ u16 f_to_bf(float f) {
    unsigned u = __float_as_uint(f);
    return (u16)((u + 0x7fff + ((u >> 16) & 1)) >> 16);  // RNE
}
__device__ __forceinline__ float4 bf4_to_f4(ushort4 v) {
    float4 r;
    r.x = __uint_as_float((unsigned)v.x << 16);
    r.y = __uint_as_float((unsigned)v.y << 16);
    r.z = __uint_as_float((unsigned)v.z << 16);
    r.w = __uint_as_float((unsigned)v.w << 16);
    return r;
}
__device__ __forceinline__ void facc(float4& a, float4 v) {
    a.x += v.x; a.y += v.y; a.z += v.z; a.w += v.w;
}
__device__ __forceinline__ float4 shfl_xor4(float4 v, int mask, int width) {
    v.x = __shfl_xor(v.x, mask, width);
    v.y = __shfl_xor(v.y, mask, width);
    v.z = __shfl_xor(v.z, mask, width);
    v.w = __shfl_xor(v.w, mask, width);
    return v;
}

template <int C>
__device__ __forceinline__ float4 gather_sum(const u16* __restrict__ HW,
                                             const int* __restrict__ col,
                                             int c0, int ps, int pe) {
    float4 a0 = make_float4(0.f, 0.f, 0.f, 0.f);
    float4 a1 = a0, a2 = a0, a3 = a0;
    int p = ps;
    for (; p + 4 <= pe; p += 4) {
        int j0 = col[p], j1 = col[p + 1], j2 = col[p + 2], j3 = col[p + 3];
        facc(a0, bf4_to_f4(*(const ushort4*)&HW[(size_t)j0 * C + c0]));
        facc(a1, bf4_to_f4(*(const ushort4*)&HW[(size_t)j1 * C + c0]));
        facc(a2, bf4_to_f4(*(const ushort4*)&HW[(size_t)j2 * C + c0]));
        facc(a3, bf4_to_f4(*(const ushort4*)&HW[(size_t)j3 * C + c0]));
    }
    for (; p < pe; p++) {
        int j = col[p];
        facc(a0, bf4_to_f4(*(const ushort4*)&HW[(size_t)j * C + c0]));
    }
    facc(a0, a1); facc(a2, a3); facc(a0, a2);
    return a0;
}

// ---------------- bucketed CSR build ----------------

__global__ void bucket_count_kernel(const int* __restrict__ dst0, const int* __restrict__ dst1,
                                    int E, int* __restrict__ bcnt, int nbuk) {
    const int* dst = blockIdx.y ? dst1 : dst0;
    int* bc = bcnt + blockIdx.y * 1024;
    __shared__ int hist[1024];
    for (int t = threadIdx.x; t < 1024; t += TPB) hist[t] = 0;
    __syncthreads();
    int base = blockIdx.x * 8192;
    int end = min(base + 8192, E);
    for (int e = base + (int)threadIdx.x; e < end; e += TPB)
        atomicAdd(&hist[dst[e] >> SH], 1);
    __syncthreads();
    for (int t = threadIdx.x; t < nbuk; t += TPB) {
        int h = hist[t];
        if (h) atomicAdd(&bc[t], h);
    }
}

__global__ void bucket_scan_kernel(const int* __restrict__ bcnt, int nbuk,
                                   int* __restrict__ boff, int* __restrict__ bcur) {
    int g = blockIdx.x;
    const int* bc = bcnt + g * 1024;
    int* bo = boff + g * 1024;
    int* bu = bcur + g * 1024;
    __shared__ int s[1024];
    int t = threadIdx.x;
    int v = (t < nbuk) ? bc[t] : 0;
    s[t] = v;
    __syncthreads();
    for (int st = 1; st < 1024; st <<= 1) {
        int u = (t >= st) ? s[t - st] : 0;
        __syncthreads();
        s[t] += u;
        __syncthreads();
    }
    if (t < nbuk) { int e = s[t] - v; bo[t] = e; bu[t] = e; }
}

__global__ void bucket_scatter_kernel(const int* __restrict__ e0, const int* __restrict__ e1,
                                      int E, int* __restrict__ bcur,
                                      int* __restrict__ ebuf0, int* __restrict__ ebuf1, int nbuk) {
    int g = blockIdx.y;
    const int* src = g ? e1 : e0;
    const int* dst = src + E;
    int* ebuf = g ? ebuf1 : ebuf0;
    int* bu = bcur + g * 1024;
    __shared__ int hist[1024];
    for (int t = threadIdx.x; t < 1024; t += TPB) hist[t] = 0;
    __syncthreads();
    int base = blockIdx.x * 4096;
    int pk[16], bk[16], rk[16];
#pragma unroll
    for (int k = 0; k < 16; k++) {
        int e = base + k * TPB + (int)threadIdx.x;
        bk[k] = -1;
        if (e < E) {
            int s = src[e], d = dst[e];
            int b = d >> SH;
            bk[k] = b;
            pk[k] = (s << SH) | (d & (BW - 1));
            rk[k] = atomicAdd(&hist[b], 1);
        }
    }
    __syncthreads();
    for (int t = threadIdx.x; t < nbuk; t += TPB) {
        int h = hist[t];
        hist[t] = h ? atomicAdd(&bu[t], h) : 0;
    }
    __syncthreads();
#pragma unroll
    for (int k = 0; k < 16; k++)
        if (bk[k] >= 0) ebuf[hist[bk[k]] + rk[k]] = pk[k];
}

// Fused: per-bucket histogram -> local scan -> off/dinv -> fill col.
__global__ void bucket_csr_kernel(const int* __restrict__ ebuf0, const int* __restrict__ ebuf1,
                                  const int* __restrict__ boff, const int* __restrict__ bcnt,
                                  int n, int E,
                                  int* __restrict__ off0, int* __restrict__ off1,
                                  float* __restrict__ dinv0, float* __restrict__ dinv1,
                                  int* __restrict__ col0, int* __restrict__ col1) {
    int g = blockIdx.y;
    int b = blockIdx.x;
    const int* ebuf = g ? ebuf1 : ebuf0;
    int* off = g ? off1 : off0;
    float* dinv = g ? dinv1 : dinv0;
    int* col = g ? col1 : col0;
    __shared__ int h[BW], nb[BW], nrank[BW];
    int tid = threadIdx.x;
    if (tid < BW) h[tid] = 0;
    __syncthreads();
    int s = boff[g * 1024 + b], e = s + bcnt[g * 1024 + b];
    for (int i = s + tid; i < e; i += TPB)
        atomicAdd(&h[ebuf[i] & (BW - 1)], 1);
    __syncthreads();
    if (tid < BW) {
        int v = h[tid];
        int x = v;
        for (int d = 1; d < BW; d <<= 1) {
            int u = __shfl_up(x, d, 64);
            if (tid >= d) x += u;
        }
        int base = s + x - v;  // exclusive
        nb[tid] = base;
        nrank[tid] = 0;
        int node = b * BW + tid;
        if (node < n) {
            off[node] = base;
            dinv[node] = rsqrtf((float)v + 1.0f);
        }
        if (node == 0) off[n] = E;
    }
    __syncthreads();
    for (int i = s + tid; i < e; i += TPB) {
        int p = ebuf[i];
        int lo = p & (BW - 1);
        int r = atomicAdd(&nrank[lo], 1);
        col[nb[lo] + r] = p >> SH;
    }
}

// ---------------- dense matmul via MFMA: Y = bf16( dinv[n] * (X @ W) ) ----------

template <int CIN, int COUT>
__global__ void matmul_kernel(const float* __restrict__ X0, const float* __restrict__ X1,
                              const float* __restrict__ W,
                              const float* __restrict__ dinv0, const float* __restrict__ dinv1,
                              u16* __restrict__ Y0, u16* __restrict__ Y1, int n) {
    constexpr int CINP = CIN + 8;
    constexpr int NT = COUT / 16;
    constexpr int KT = CIN / 32;
    __shared__ u16 Xs[64 * CINP];
    __shared__ u16 Wt[COUT * CINP];

    int g = blockIdx.y;
    const float* X = g ? X1 : X0;
    const float* dinv = g ? dinv1 : dinv0;
    u16* Y = g ? Y1 : Y0;
    int nb0 = blockIdx.x * 64;

    for (int i = threadIdx.x; i < 64 * (CIN / 4); i += TPB) {
        int nn = i / (CIN / 4), kc = i % (CIN / 4);
        float4 v = make_float4(0.f, 0.f, 0.f, 0.f);
        if (nb0 + nn < n) v = *(const float4*)&X[(size_t)(nb0 + nn) * CIN + 4 * kc];
        ushort4 b;
        b.x = f_to_bf(v.x); b.y = f_to_bf(v.y); b.z = f_to_bf(v.z); b.w = f_to_bf(v.w);
        *(ushort4*)&Xs[nn * CINP + 4 * kc] = b;
    }
    for (int i = threadIdx.x; i < CIN * (COUT / 4); i += TPB) {
        int k = i / (COUT / 4), nc4 = i % (COUT / 4);
        float4 v = *(const float4*)&W[(size_t)k * COUT + 4 * nc4];
        Wt[(4 * nc4 + 0) * CINP + k] = f_to_bf(v.x);
        Wt[(4 * nc4 + 1) * CINP + k] = f_to_bf(v.y);
        Wt[(4 * nc4 + 2) * CINP + k] = f_to_bf(v.z);
        Wt[(4 * nc4 + 3) * CINP + k] = f_to_bf(v.w);
    }
    __syncthreads();

    int lane = threadIdx.x & 63;
    int w = threadIdx.x >> 6;
    int m = lane & 15;
    int quad = lane >> 4;

    f32x4 acc[NT];
#pragma unroll
    for (int t = 0; t < NT; t++) acc[t] = (f32x4){0.f, 0.f, 0.f, 0.f};
#pragma unroll
    for (int kt = 0; kt < KT; kt++) {
        int k0 = kt * 32 + quad * 8;
        bf16x8 a = *(const bf16x8*)&Xs[(w * 16 + m) * CINP + k0];
#pragma unroll
        for (int t = 0; t < NT; t++) {
            bf16x8 b = *(const bf16x8*)&Wt[(t * 16 + m) * CINP + k0];
            acc[t] = __builtin_amdgcn_mfma_f32_16x16x32_bf16(a, b, acc[t], 0, 0, 0);
        }
    }
#pragma unroll
    for (int r = 0; r < 4; r++) {
        int node = nb0 + w * 16 + quad * 4 + r;
        if (node < n) {
            float d = dinv[node];
#pragma unroll
            for (int t = 0; t < NT; t++)
                Y[(size_t)node * COUT + t * 16 + m] = f_to_bf(acc[t][r] * d);
        }
    }
}

// ---------------- GCN aggregation (gather over CSR-by-dst, bf16 payload) -------------

template <int C, int SPLIT, bool RELU>
__global__ void agg_kernel(const u16* __restrict__ HW0, const u16* __restrict__ HW1,
                           const int* __restrict__ off0, const int* __restrict__ off1,
                           const int* __restrict__ col0, const int* __restrict__ col1,
                           const float* __restrict__ dinv0, const float* __restrict__ dinv1,
                           const float* __restrict__ bias,
                           float* __restrict__ out0, float* __restrict__ out1, int n) {
    int g = blockIdx.y;
    const u16* HW = g ? HW1 : HW0;
    const int* off = g ? off1 : off0;
    const int* col = g ? col1 : col0;
    const float* dinv = g ? dinv1 : dinv0;
    float* outp = g ? out1 : out0;
    constexpr int CH = C / 4;
    constexpr int TPN = CH * SPLIT;
    int tid = blockIdx.x * blockDim.x + threadIdx.x;
    int node = tid / TPN;
    if (node >= n) return;
    int part = tid % TPN;
    int sp = part / CH;
    int c0 = (part % CH) * 4;
    int s = off[node], e = off[node + 1];
    int len = e - s;
    int chunk = (len + SPLIT - 1) / SPLIT;
    int ps = s + sp * chunk;
    int pe = min(ps + chunk, e);
    float4 r = gather_sum<C>(HW, col, c0, ps, pe);
#pragma unroll
    for (int m = CH; m < TPN; m <<= 1) facc(r, shfl_xor4(r, m, TPN));
    if (sp == 0) {
        float di = dinv[node];
        float4 self = bf4_to_f4(*(const ushort4*)&HW[(size_t)node * C + c0]);
        float4 b4 = *(const float4*)&bias[c0];
        float4 o;
        o.x = di * (r.x + self.x) + b4.x;
        o.y = di * (r.y + self.y) + b4.y;
        o.z = di * (r.z + self.z) + b4.z;
        o.w = di * (r.w + self.w) + b4.w;
        if (RELU) {
            o.x = fmaxf(o.x, 0.f); o.y = fmaxf(o.y, 0.f);
            o.z = fmaxf(o.z, 0.f); o.w = fmaxf(o.w, 0.f);
        }
        *(float4*)&outp[(size_t)node * C + c0] = o;
    }
}

// Layer-3 aggregation (C=16, SPLIT=4) + per-block colsum partials (NO atomics).
__global__ void agg16_kernel(const u16* __restrict__ HW0, const u16* __restrict__ HW1,
                             const int* __restrict__ off0, const int* __restrict__ off1,
                             const int* __restrict__ col0, const int* __restrict__ col1,
                             const float* __restrict__ dinv0, const float* __restrict__ dinv1,
                             const float* __restrict__ bias,
                             float* __restrict__ out0, float* __restrict__ out1,
                             float* __restrict__ pcol, int n) {
    int g = blockIdx.y;
    const u16* HW = g ? HW1 : HW0;
    const int* off = g ? off1 : off0;
    const int* col = g ? col1 : col0;
    const float* dinv = g ? dinv1 : dinv0;
    float* outp = g ? out1 : out0;
    int tid = blockIdx.x * blockDim.x + threadIdx.x;
    int node = tid / 16;
    int part = tid % 16;
    int sp = part / 4;
    int c0 = (part % 4) * 4;
    float4 o = make_float4(0.f, 0.f, 0.f, 0.f);
    if (node < n) {
        int s = off[node], e = off[node + 1];
        int len = e - s;
        int chunk = (len + 3) / 4;
        int ps = s + sp * chunk;
        int pe = min(ps + chunk, e);
        float4 r = gather_sum<16>(HW, col, c0, ps, pe);
        facc(r, shfl_xor4(r, 4, 16));
        facc(r, shfl_xor4(r, 8, 16));
        if (sp == 0) {
            float di = dinv[node];
            float4 self = bf4_to_f4(*(const ushort4*)&HW[(size_t)node * 16 + c0]);
            float4 b4 = *(const float4*)&bias[c0];
            o.x = di * (r.x + self.x) + b4.x;
            o.y = di * (r.y + self.y) + b4.y;
            o.z = di * (r.z + self.z) + b4.z;
            o.w = di * (r.w + self.w) + b4.w;
            *(float4*)&outp[(size_t)node * 16 + c0] = o;
        }
    }
    // per-block colsum partial (only sp==0 lanes hold data)
    __shared__ float4 sd[TPB];
    sd[threadIdx.x] = (node < n && sp == 0) ? o : make_float4(0.f, 0.f, 0.f, 0.f);
    __syncthreads();
    if (threadIdx.x < 64) {
        float4 a = sd[threadIdx.x];
        facc(a, sd[threadIdx.x + 64]);
        facc(a, sd[threadIdx.x + 128]);
        facc(a, sd[threadIdx.x + 192]);
        sd[threadIdx.x] = a;
    }
    __syncthreads();
    if (threadIdx.x < 16) {
        float4 a = sd[threadIdx.x];
        facc(a, sd[threadIdx.x + 16]);
        facc(a, sd[threadIdx.x + 32]);
        facc(a, sd[threadIdx.x + 48]);
        sd[threadIdx.x] = a;
    }
    __syncthreads();
    if (threadIdx.x < 4)
        *(float4*)&pcol[((size_t)g * gridDim.x + blockIdx.x) * 16 + threadIdx.x * 4] = sd[threadIdx.x];
}

// ---------------- cvec: coalesced reduce of pcol partials + tanh(mean @ Wa) ----------
// One block per graph; float4-coalesced tree reduction (nb16*4 float4s).

__global__ void cvec_kernel(const float* __restrict__ pcol, int nb16, float n_inv,
                            const float* __restrict__ Wa, float* __restrict__ cvec) {
    int g = blockIdx.x;
    const float4* p4 = (const float4*)(pcol + (size_t)g * nb16 * 16);
    __shared__ float4 sd[TPB];
    __shared__ float cs[16];
    int c4 = threadIdx.x & 3;   // which float4 of the 16 channels
    int row = threadIdx.x >> 2; // 64 rows
    float4 acc = make_float4(0.f, 0.f, 0.f, 0.f);
    for (int r = row; r < nb16; r += 64) facc(acc, p4[(size_t)r * 4 + c4]);
    sd[threadIdx.x] = acc;
    __syncthreads();
    if (threadIdx.x < 64) {
        float4 a = sd[threadIdx.x];
        facc(a, sd[threadIdx.x + 64]);
        facc(a, sd[threadIdx.x + 128]);
        facc(a, sd[threadIdx.x + 192]);
        sd[threadIdx.x] = a;
    }
    __syncthreads();
    if (threadIdx.x < 16) {
        float4 a = sd[threadIdx.x];
        facc(a, sd[threadIdx.x + 16]);
        facc(a, sd[threadIdx.x + 32]);
        facc(a, sd[threadIdx.x + 48]);
        sd[threadIdx.x] = a;
    }
    __syncthreads();
    if (threadIdx.x < 4) {
        float4 a = sd[threadIdx.x];       // rows 0..3 of column group threadIdx.x
        facc(a, sd[threadIdx.x + 4]);
        facc(a, sd[threadIdx.x + 8]);
        facc(a, sd[threadIdx.x + 12]);
        cs[threadIdx.x * 4 + 0] = a.x * n_inv;
        cs[threadIdx.x * 4 + 1] = a.y * n_inv;
        cs[threadIdx.x * 4 + 2] = a.z * n_inv;
        cs[threadIdx.x * 4 + 3] = a.w * n_inv;
    }
    __syncthreads();
    if (threadIdx.x < 16) {
        float acc2 = 0.f;
        for (int i = 0; i < 16; i++) acc2 += cs[i] * Wa[i * 16 + threadIdx.x];
        cvec[g * 16 + threadIdx.x] = tanhf(acc2);
    }
}

// ---------------- attention pooling (per-block partials, no atomics) ----------------

__global__ void pool_kernel(const float* __restrict__ H0, const float* __restrict__ H1, int n,
                            const float* __restrict__ cvec, float* __restrict__ ppool) {
    int g = blockIdx.y;
    const float* H = g ? H1 : H0;
    int c = threadIdx.x & 15;
    float cv = cvec[g * 16 + c];
    int w = (blockIdx.x * blockDim.x + threadIdx.x) / 16;
    int stride = (gridDim.x * blockDim.x) / 16;
    float acc = 0.f;
    for (int node = w; node < n; node += stride) {
        float x = H[(size_t)node * 16 + c];
        float p = x * cv;
        p += __shfl_xor(p, 1, 16);
        p += __shfl_xor(p, 2, 16);
        p += __shfl_xor(p, 4, 16);
        p += __shfl_xor(p, 8, 16);
        float s = 1.f / (1.f + __expf(-p));
        acc += s * x;
    }
    __shared__ float sdata[TPB];
    sdata[threadIdx.x] = acc;
    __syncthreads();
    if (threadIdx.x < 16) {
        float s = 0.f;
        for (int t = threadIdx.x; t < TPB; t += 16) s += sdata[t];
        ppool[((size_t)g * gridDim.x + blockIdx.x) * 16 + threadIdx.x] = s;
    }
}

// ---------------- final: reduce pool partials + tensor-network scoring ----------------

__global__ void final_kernel(const float* __restrict__ ppool, int nbp,
                             const float* __restrict__ Wt, const float* __restrict__ Wb,
                             const float* __restrict__ bt, const float* __restrict__ Wfc,
                             const float* __restrict__ bfc, const float* __restrict__ Wsc,
                             const float* __restrict__ bsc, float* __restrict__ out) {
    __shared__ float rep[32], scores[16], tvec[16];
    int t = threadIdx.x;
    if (t < 32) {
        int g = t >> 4, c = t & 15;
        float s = 0.f;
        for (int b = 0; b < nbp; b++) s += ppool[((size_t)g * nbp + b) * 16 + c];
        rep[t] = s;
    }
    __syncthreads();
    if (t < 16) {
        float bil = 0.f;
        for (int i = 0; i < 16; i++) {
            float a = rep[i];
            for (int j = 0; j < 16; j++) bil += a * rep[16 + j] * Wt[(i * 16 + j) * 16 + t];
        }
        float blk = 0.f;
        for (int m = 0; m < 16; m++)
            blk += Wb[t * 32 + m] * rep[m] + Wb[t * 32 + 16 + m] * rep[16 + m];
        scores[t] = fmaxf(bil + blk + bt[t], 0.f);
    }
    __syncthreads();
    if (t < 16) {
        float acc = bfc[t];
        for (int k = 0; k < 16; k++) acc += scores[k] * Wfc[k * 16 + t];
        tvec[t] = tanhf(acc);
    }
    __syncthreads();
    if (t == 0) {
        float acc = bsc[0];
        for (int j = 0; j < 16; j++) acc += tvec[j] * Wsc[j];
        out[0] = 1.f / (1.f + __expf(-acc));
    }
}

// ---------------- launcher ----------------

extern "C" void kernel_launch(void* const* d_in, const int* in_sizes, int n_in,
                              void* d_out, int out_size, void* d_ws, size_t ws_size,
                              hipStream_t stream) {
    const float* X1 = (const float*)d_in[0];
    const float* X2 = (const float*)d_in[1];
    const int* edges1 = (const int*)d_in[2];
    const int* edges2 = (const int*)d_in[3];
    const float* W1 = (const float*)d_in[4];
    const float* b1 = (const float*)d_in[5];
    const float* W2 = (const float*)d_in[6];
    const float* b2 = (const float*)d_in[7];
    const float* W3 = (const float*)d_in[8];
    const float* b3 = (const float*)d_in[9];
    const float* Wa = (const float*)d_in[10];
    const float* Wt = (const float*)d_in[11];
    const float* Wb = (const float*)d_in[12];
    const float* bt = (const float*)d_in[13];
    const float* Wfc = (const float*)d_in[14];
    const float* bfc = (const float*)d_in[15];
    const float* Wsc = (const float*)d_in[16];
    const float* bsc = (const float*)d_in[17];
    float* out = (float*)d_out;

    const int N = in_sizes[0] / 96;
    const int E = in_sizes[2] / 2;
    const int NBUK = (N + BW - 1) / BW;  // buckets (must be <= 1024)

    char* ws = (char*)d_ws;
    size_t o = 0;
    auto alloc = [&](size_t bytes) {
        void* p = ws + o;
        o += (bytes + 255) & ~(size_t)255;
        return p;
    };
    int* bcnt = (int*)alloc((size_t)2 * 1024 * 4);
    int* boff = (int*)alloc((size_t)2 * 1024 * 4);
    int* bcur = (int*)alloc((size_t)2 * 1024 * 4);
    int* off0 = (int*)alloc((size_t)(N + 1) * 4);
    int* off1 = (int*)alloc((size_t)(N + 1) * 4);
    int* col0 = (int*)alloc((size_t)E * 4);
    int* col1 = (int*)alloc((size_t)E * 4);
    float* dinv0 = (float*)alloc((size_t)N * 4);
    float* dinv1 = (float*)alloc((size_t)N * 4);
    int* ebuf0 = (int*)alloc((size_t)E * 4);
    int* ebuf1 = (int*)alloc((size_t)E * 4);
    u16* hwb0 = (u16*)alloc((size_t)N * 64 * 2);   // bf16 gather payload
    u16* hwb1 = (u16*)alloc((size_t)N * 64 * 2);
    float* bufB0 = (float*)alloc((size_t)N * 64 * 4);  // fp32 agg outputs
    float* bufB1 = (float*)alloc((size_t)N * 64 * 4);

    const int gB1 = (E + 8191) / 8192;
    const int gB2 = (E + 4095) / 4096;
    const int g16 = ((size_t)N * 16 + TPB - 1) / TPB;  // all aggs run 16 threads/node
    const int gMM = (N + 63) / 64;                     // MFMA matmul: 64 nodes/block
    const int gPool = 256;                             // pool blocks per graph

    float* pcol = (float*)alloc((size_t)2 * g16 * 16 * 4);   // agg16 colsum partials
    float* cvecArr = (float*)alloc(32 * 4);
    float* ppool = (float*)alloc((size_t)2 * gPool * 16 * 4);

    hipMemsetAsync(bcnt, 0, (size_t)2 * 1024 * 4, stream);

    // bucketed CSR build (both graphs per dispatch)
    bucket_count_kernel<<<dim3(gB1, 2), TPB, 0, stream>>>(edges1 + E, edges2 + E, E, bcnt, NBUK);
    bucket_scan_kernel<<<2, 1024, 0, stream>>>(bcnt, NBUK, boff, bcur);
    bucket_scatter_kernel<<<dim3(gB2, 2), TPB, 0, stream>>>(edges1, edges2, E, bcur, ebuf0, ebuf1, NBUK);
    bucket_csr_kernel<<<dim3(NBUK, 2), TPB, 0, stream>>>(ebuf0, ebuf1, boff, bcnt, N, E,
                                                         off0, off1, dinv0, dinv1, col0, col1);

    // layer 1: 96 -> 64 (MFMA), agg + relu (SPLIT=1: 16 threads/node)
    matmul_kernel<96, 64><<<dim3(gMM, 2), TPB, 0, stream>>>(X1, X2, W1, dinv0, dinv1, hwb0, hwb1, N);
    agg_kernel<64, 1, true><<<dim3(g16, 2), TPB, 0, stream>>>(
        hwb0, hwb1, off0, off1, col0, col1, dinv0, dinv1, b1, bufB0, bufB1, N);
    // layer 2: 64 -> 32 (MFMA), agg + relu (SPLIT=2)
    matmul_kernel<64, 32><<<dim3(gMM, 2), TPB, 0, stream>>>(bufB0, bufB1, W2, dinv0, dinv1, hwb0, hwb1, N);
    agg_kernel<32, 2, true><<<dim3(g16, 2), TPB, 0, stream>>>(
        hwb0, hwb1, off0, off1, col0, col1, dinv0, dinv1, b2, bufB0, bufB1, N);
    // layer 3: 32 -> 16 (MFMA), agg + colsum partials (SPLIT=4)
    matmul_kernel<32, 16><<<dim3(gMM, 2), TPB, 0, stream>>>(bufB0, bufB1, W3, dinv0, dinv1, hwb0, hwb1, N);
    agg16_kernel<<<dim3(g16, 2), TPB, 0, stream>>>(
        hwb0, hwb1, off0, off1, col0, col1, dinv0, dinv1, b3, bufB0, bufB1, pcol, N);

    // attention pooling: coalesced cvec reduce, then high-occupancy pool partials
    cvec_kernel<<<2, TPB, 0, stream>>>(pcol, g16, 1.0f / (float)N, Wa, cvecArr);
    pool_kernel<<<dim3(gPool, 2), TPB, 0, stream>>>(bufB0, bufB1, N, cvecArr, ppool);
    final_kernel<<<1, 256, 0, stream>>>(ppool, gPool, Wt, Wb, bt, Wfc, bfc, Wsc, bsc, out);
}

// Round 14
// 283.795 us; speedup vs baseline: 5.8292x; 1.1427x over previous
//
#include <hip/hip_runtime.h>
#include <hip/hip_bf16.h>

#define TPB 256
#define SH 6
#define BW 64  // nodes per bucket = 1<<SH; NBUK must be <= 1024 (N <= 65536)

typedef unsigned short u16;
typedef __attribute__((ext_vector_type(8))) __bf16 bf16x8;  // MFMA A/B frag (4 VGPRs)
typedef __attribute__((ext_vector_type(4))) float f32x4;    // MFMA C/D frag

// bf16 helpers: payload stored as bf16 (halves gather BW), accumulate in fp32.
__device__ __forceinline__ u16 f_to_bf(float f) {
    unsigned u = __float_as_uint(f);
    return (u16)((u + 0x7fff + ((u >> 16) & 1)) >> 16);  // RNE
}
__device__ __forceinline__ float4 bf4_to_f4(ushort4 v) {
    float4 r;
    r.x = __uint_as_float((unsigned)v.x << 16);
    r.y = __uint_as_float((unsigned)v.y << 16);
    r.z = __uint_as_float((unsigned)v.z << 16);
    r.w = __uint_as_float((unsigned)v.w << 16);
    return r;
}
__device__ __forceinline__ void facc(float4& a, float4 v) {
    a.x += v.x; a.y += v.y; a.z += v.z; a.w += v.w;
}
__device__ __forceinline__ float4 shfl_xor4(float4 v, int mask, int width) {
    v.x = __shfl_xor(v.x, mask, width);
    v.y = __shfl_xor(v.y, mask, width);
    v.z = __shfl_xor(v.z, mask, width);
    v.w = __shfl_xor(v.w, mask, width);
    return v;
}

template <int C>
__device__ __forceinline__ float4 gather_sum(const u16* __restrict__ HW,
                                             const int* __restrict__ col,
                                             int c0, int ps, int pe) {
    float4 a0 = make_float4(0.f, 0.f, 0.f, 0.f);
    float4 a1 = a0, a2 = a0, a3 = a0;
    int p = ps;
    for (; p + 4 <= pe; p += 4) {
        int j0 = col[p], j1 = col[p + 1], j2 = col[p + 2], j3 = col[p + 3];
        facc(a0, bf4_to_f4(*(const ushort4*)&HW[(size_t)j0 * C + c0]));
        facc(a1, bf4_to_f4(*(const ushort4*)&HW[(size_t)j1 * C + c0]));
        facc(a2, bf4_to_f4(*(const ushort4*)&HW[(size_t)j2 * C + c0]));
        facc(a3, bf4_to_f4(*(const ushort4*)&HW[(size_t)j3 * C + c0]));
    }
    for (; p < pe; p++) {
        int j = col[p];
        facc(a0, bf4_to_f4(*(const ushort4*)&HW[(size_t)j * C + c0]));
    }
    facc(a0, a1); facc(a2, a3); facc(a0, a2);
    return a0;
}

// ---------------- bucketed CSR build ----------------

__global__ void bucket_count_kernel(const int* __restrict__ dst0, const int* __restrict__ dst1,
                                    int E, int* __restrict__ bcnt, int nbuk) {
    const int* dst = blockIdx.y ? dst1 : dst0;
    int* bc = bcnt + blockIdx.y * 1024;
    __shared__ int hist[1024];
    for (int t = threadIdx.x; t < 1024; t += TPB) hist[t] = 0;
    __syncthreads();
    int base = blockIdx.x * 8192;
    int end = min(base + 8192, E);
    for (int e = base + (int)threadIdx.x; e < end; e += TPB)
        atomicAdd(&hist[dst[e] >> SH], 1);
    __syncthreads();
    for (int t = threadIdx.x; t < nbuk; t += TPB) {
        int h = hist[t];
        if (h) atomicAdd(&bc[t], h);
    }
}

__global__ void bucket_scan_kernel(const int* __restrict__ bcnt, int nbuk,
                                   int* __restrict__ boff, int* __restrict__ bcur) {
    int g = blockIdx.x;
    const int* bc = bcnt + g * 1024;
    int* bo = boff + g * 1024;
    int* bu = bcur + g * 1024;
    __shared__ int s[1024];
    int t = threadIdx.x;
    int v = (t < nbuk) ? bc[t] : 0;
    s[t] = v;
    __syncthreads();
    for (int st = 1; st < 1024; st <<= 1) {
        int u = (t >= st) ? s[t - st] : 0;
        __syncthreads();
        s[t] += u;
        __syncthreads();
    }
    if (t < nbuk) { int e = s[t] - v; bo[t] = e; bu[t] = e; }
}

__global__ void bucket_scatter_kernel(const int* __restrict__ e0, const int* __restrict__ e1,
                                      int E, int* __restrict__ bcur,
                                      int* __restrict__ ebuf0, int* __restrict__ ebuf1, int nbuk) {
    int g = blockIdx.y;
    const int* src = g ? e1 : e0;
    const int* dst = src + E;
    int* ebuf = g ? ebuf1 : ebuf0;
    int* bu = bcur + g * 1024;
    __shared__ int hist[1024];
    for (int t = threadIdx.x; t < 1024; t += TPB) hist[t] = 0;
    __syncthreads();
    int base = blockIdx.x * 4096;
    int pk[16], bk[16], rk[16];
#pragma unroll
    for (int k = 0; k < 16; k++) {
        int e = base + k * TPB + (int)threadIdx.x;
        bk[k] = -1;
        if (e < E) {
            int s = src[e], d = dst[e];
            int b = d >> SH;
            bk[k] = b;
            pk[k] = (s << SH) | (d & (BW - 1));
            rk[k] = atomicAdd(&hist[b], 1);
        }
    }
    __syncthreads();
    for (int t = threadIdx.x; t < nbuk; t += TPB) {
        int h = hist[t];
        hist[t] = h ? atomicAdd(&bu[t], h) : 0;
    }
    __syncthreads();
#pragma unroll
    for (int k = 0; k < 16; k++)
        if (bk[k] >= 0) ebuf[hist[bk[k]] + rk[k]] = pk[k];
}

// Fused: per-bucket histogram -> local scan -> off/dinv -> fill col.
__global__ void bucket_csr_kernel(const int* __restrict__ ebuf0, const int* __restrict__ ebuf1,
                                  const int* __restrict__ boff, const int* __restrict__ bcnt,
                                  int n, int E,
                                  int* __restrict__ off0, int* __restrict__ off1,
                                  float* __restrict__ dinv0, float* __restrict__ dinv1,
                                  int* __restrict__ col0, int* __restrict__ col1) {
    int g = blockIdx.y;
    int b = blockIdx.x;
    const int* ebuf = g ? ebuf1 : ebuf0;
    int* off = g ? off1 : off0;
    float* dinv = g ? dinv1 : dinv0;
    int* col = g ? col1 : col0;
    __shared__ int h[BW], nb[BW], nrank[BW];
    int tid = threadIdx.x;
    if (tid < BW) h[tid] = 0;
    __syncthreads();
    int s = boff[g * 1024 + b], e = s + bcnt[g * 1024 + b];
    for (int i = s + tid; i < e; i += TPB)
        atomicAdd(&h[ebuf[i] & (BW - 1)], 1);
    __syncthreads();
    if (tid < BW) {
        int v = h[tid];
        int x = v;
        for (int d = 1; d < BW; d <<= 1) {
            int u = __shfl_up(x, d, 64);
            if (tid >= d) x += u;
        }
        int base = s + x - v;  // exclusive
        nb[tid] = base;
        nrank[tid] = 0;
        int node = b * BW + tid;
        if (node < n) {
            off[node] = base;
            dinv[node] = rsqrtf((float)v + 1.0f);
        }
        if (node == 0) off[n] = E;
    }
    __syncthreads();
    for (int i = s + tid; i < e; i += TPB) {
        int p = ebuf[i];
        int lo = p & (BW - 1);
        int r = atomicAdd(&nrank[lo], 1);
        col[nb[lo] + r] = p >> SH;
    }
}

// ---------------- dense matmul via MFMA: Y = bf16( dinv[n] * (X @ W) ) ----------

template <int CIN, int COUT>
__global__ void matmul_kernel(const float* __restrict__ X0, const float* __restrict__ X1,
                              const float* __restrict__ W,
                              const float* __restrict__ dinv0, const float* __restrict__ dinv1,
                              u16* __restrict__ Y0, u16* __restrict__ Y1, int n) {
    constexpr int CINP = CIN + 8;
    constexpr int NT = COUT / 16;
    constexpr int KT = CIN / 32;
    __shared__ u16 Xs[64 * CINP];
    __shared__ u16 Wt[COUT * CINP];

    int g = blockIdx.y;
    const float* X = g ? X1 : X0;
    const float* dinv = g ? dinv1 : dinv0;
    u16* Y = g ? Y1 : Y0;
    int nb0 = blockIdx.x * 64;

    for (int i = threadIdx.x; i < 64 * (CIN / 4); i += TPB) {
        int nn = i / (CIN / 4), kc = i % (CIN / 4);
        float4 v = make_float4(0.f, 0.f, 0.f, 0.f);
        if (nb0 + nn < n) v = *(const float4*)&X[(size_t)(nb0 + nn) * CIN + 4 * kc];
        ushort4 b;
        b.x = f_to_bf(v.x); b.y = f_to_bf(v.y); b.z = f_to_bf(v.z); b.w = f_to_bf(v.w);
        *(ushort4*)&Xs[nn * CINP + 4 * kc] = b;
    }
    for (int i = threadIdx.x; i < CIN * (COUT / 4); i += TPB) {
        int k = i / (COUT / 4), nc4 = i % (COUT / 4);
        float4 v = *(const float4*)&W[(size_t)k * COUT + 4 * nc4];
        Wt[(4 * nc4 + 0) * CINP + k] = f_to_bf(v.x);
        Wt[(4 * nc4 + 1) * CINP + k] = f_to_bf(v.y);
        Wt[(4 * nc4 + 2) * CINP + k] = f_to_bf(v.z);
        Wt[(4 * nc4 + 3) * CINP + k] = f_to_bf(v.w);
    }
    __syncthreads();

    int lane = threadIdx.x & 63;
    int w = threadIdx.x >> 6;
    int m = lane & 15;
    int quad = lane >> 4;

    f32x4 acc[NT];
#pragma unroll
    for (int t = 0; t < NT; t++) acc[t] = (f32x4){0.f, 0.f, 0.f, 0.f};
#pragma unroll
    for (int kt = 0; kt < KT; kt++) {
        int k0 = kt * 32 + quad * 8;
        bf16x8 a = *(const bf16x8*)&Xs[(w * 16 + m) * CINP + k0];
#pragma unroll
        for (int t = 0; t < NT; t++) {
            bf16x8 b = *(const bf16x8*)&Wt[(t * 16 + m) * CINP + k0];
            acc[t] = __builtin_amdgcn_mfma_f32_16x16x32_bf16(a, b, acc[t], 0, 0, 0);
        }
    }
#pragma unroll
    for (int r = 0; r < 4; r++) {
        int node = nb0 + w * 16 + quad * 4 + r;
        if (node < n) {
            float d = dinv[node];
#pragma unroll
            for (int t = 0; t < NT; t++)
                Y[(size_t)node * COUT + t * 16 + m] = f_to_bf(acc[t][r] * d);
        }
    }
}

// ---------------- GCN aggregation (gather over CSR-by-dst, bf16 payload) -------------

template <int C, int SPLIT, bool RELU>
__global__ void agg_kernel(const u16* __restrict__ HW0, const u16* __restrict__ HW1,
                           const int* __restrict__ off0, const int* __restrict__ off1,
                           const int* __restrict__ col0, const int* __restrict__ col1,
                           const float* __restrict__ dinv0, const float* __restrict__ dinv1,
                           const float* __restrict__ bias,
                           float* __restrict__ out0, float* __restrict__ out1, int n) {
    int g = blockIdx.y;
    const u16* HW = g ? HW1 : HW0;
    const int* off = g ? off1 : off0;
    const int* col = g ? col1 : col0;
    const float* dinv = g ? dinv1 : dinv0;
    float* outp = g ? out1 : out0;
    constexpr int CH = C / 4;
    constexpr int TPN = CH * SPLIT;
    int tid = blockIdx.x * blockDim.x + threadIdx.x;
    int node = tid / TPN;
    if (node >= n) return;
    int part = tid % TPN;
    int sp = part / CH;
    int c0 = (part % CH) * 4;
    int s = off[node], e = off[node + 1];
    int len = e - s;
    int chunk = (len + SPLIT - 1) / SPLIT;
    int ps = s + sp * chunk;
    int pe = min(ps + chunk, e);
    float4 r = gather_sum<C>(HW, col, c0, ps, pe);
#pragma unroll
    for (int m = CH; m < TPN; m <<= 1) facc(r, shfl_xor4(r, m, TPN));
    if (sp == 0) {
        float di = dinv[node];
        float4 self = bf4_to_f4(*(const ushort4*)&HW[(size_t)node * C + c0]);
        float4 b4 = *(const float4*)&bias[c0];
        float4 o;
        o.x = di * (r.x + self.x) + b4.x;
        o.y = di * (r.y + self.y) + b4.y;
        o.z = di * (r.z + self.z) + b4.z;
        o.w = di * (r.w + self.w) + b4.w;
        if (RELU) {
            o.x = fmaxf(o.x, 0.f); o.y = fmaxf(o.y, 0.f);
            o.z = fmaxf(o.z, 0.f); o.w = fmaxf(o.w, 0.f);
        }
        *(float4*)&outp[(size_t)node * C + c0] = o;
    }
}

// Layer-3 aggregation (C=16, SPLIT=4) + per-block colsum partials (NO atomics).
__global__ void agg16_kernel(const u16* __restrict__ HW0, const u16* __restrict__ HW1,
                             const int* __restrict__ off0, const int* __restrict__ off1,
                             const int* __restrict__ col0, const int* __restrict__ col1,
                             const float* __restrict__ dinv0, const float* __restrict__ dinv1,
                             const float* __restrict__ bias,
                             float* __restrict__ out0, float* __restrict__ out1,
                             float* __restrict__ pcol, int n) {
    int g = blockIdx.y;
    const u16* HW = g ? HW1 : HW0;
    const int* off = g ? off1 : off0;
    const int* col = g ? col1 : col0;
    const float* dinv = g ? dinv1 : dinv0;
    float* outp = g ? out1 : out0;
    int tid = blockIdx.x * blockDim.x + threadIdx.x;
    int node = tid / 16;
    int part = tid % 16;
    int sp = part / 4;
    int c0 = (part % 4) * 4;
    float4 o = make_float4(0.f, 0.f, 0.f, 0.f);
    if (node < n) {
        int s = off[node], e = off[node + 1];
        int len = e - s;
        int chunk = (len + 3) / 4;
        int ps = s + sp * chunk;
        int pe = min(ps + chunk, e);
        float4 r = gather_sum<16>(HW, col, c0, ps, pe);
        facc(r, shfl_xor4(r, 4, 16));
        facc(r, shfl_xor4(r, 8, 16));
        if (sp == 0) {
            float di = dinv[node];
            float4 self = bf4_to_f4(*(const ushort4*)&HW[(size_t)node * 16 + c0]);
            float4 b4 = *(const float4*)&bias[c0];
            o.x = di * (r.x + self.x) + b4.x;
            o.y = di * (r.y + self.y) + b4.y;
            o.z = di * (r.z + self.z) + b4.z;
            o.w = di * (r.w + self.w) + b4.w;
            *(float4*)&outp[(size_t)node * 16 + c0] = o;
        }
    }
    // per-block colsum partial (only sp==0 lanes hold data)
    __shared__ float4 sd[TPB];
    sd[threadIdx.x] = (node < n && sp == 0) ? o : make_float4(0.f, 0.f, 0.f, 0.f);
    __syncthreads();
    if (threadIdx.x < 64) {
        float4 a = sd[threadIdx.x];
        facc(a, sd[threadIdx.x + 64]);
        facc(a, sd[threadIdx.x + 128]);
        facc(a, sd[threadIdx.x + 192]);
        sd[threadIdx.x] = a;
    }
    __syncthreads();
    if (threadIdx.x < 16) {
        float4 a = sd[threadIdx.x];
        facc(a, sd[threadIdx.x + 16]);
        facc(a, sd[threadIdx.x + 32]);
        facc(a, sd[threadIdx.x + 48]);
        sd[threadIdx.x] = a;
    }
    __syncthreads();
    if (threadIdx.x < 4)
        *(float4*)&pcol[((size_t)g * gridDim.x + blockIdx.x) * 16 + threadIdx.x * 4] = sd[threadIdx.x];
}

// ---------------- cvec: coalesced reduce of pcol partials + tanh(mean @ Wa) ----------

__global__ void cvec_kernel(const float* __restrict__ pcol, int nb16, float n_inv,
                            const float* __restrict__ Wa, float* __restrict__ cvec) {
    int g = blockIdx.x;
    const float4* p4 = (const float4*)(pcol + (size_t)g * nb16 * 16);
    __shared__ float4 sd[TPB];
    __shared__ float cs[16];
    int c4 = threadIdx.x & 3;   // which float4 of the 16 channels
    int row = threadIdx.x >> 2; // 64 rows
    float4 acc = make_float4(0.f, 0.f, 0.f, 0.f);
    for (int r = row; r < nb16; r += 64) facc(acc, p4[(size_t)r * 4 + c4]);
    sd[threadIdx.x] = acc;
    __syncthreads();
    if (threadIdx.x < 64) {
        float4 a = sd[threadIdx.x];
        facc(a, sd[threadIdx.x + 64]);
        facc(a, sd[threadIdx.x + 128]);
        facc(a, sd[threadIdx.x + 192]);
        sd[threadIdx.x] = a;
    }
    __syncthreads();
    if (threadIdx.x < 16) {
        float4 a = sd[threadIdx.x];
        facc(a, sd[threadIdx.x + 16]);
        facc(a, sd[threadIdx.x + 32]);
        facc(a, sd[threadIdx.x + 48]);
        sd[threadIdx.x] = a;
    }
    __syncthreads();
    if (threadIdx.x < 4) {
        float4 a = sd[threadIdx.x];
        facc(a, sd[threadIdx.x + 4]);
        facc(a, sd[threadIdx.x + 8]);
        facc(a, sd[threadIdx.x + 12]);
        cs[threadIdx.x * 4 + 0] = a.x * n_inv;
        cs[threadIdx.x * 4 + 1] = a.y * n_inv;
        cs[threadIdx.x * 4 + 2] = a.z * n_inv;
        cs[threadIdx.x * 4 + 3] = a.w * n_inv;
    }
    __syncthreads();
    if (threadIdx.x < 16) {
        float acc2 = 0.f;
#pragma unroll
        for (int i = 0; i < 16; i++) acc2 += cs[i] * Wa[i * 16 + threadIdx.x];
        cvec[g * 16 + threadIdx.x] = tanhf(acc2);
    }
}

// ---------------- attention pooling (per-block partials, no atomics) ----------------

__global__ void pool_kernel(const float* __restrict__ H0, const float* __restrict__ H1, int n,
                            const float* __restrict__ cvec, float* __restrict__ ppool) {
    int g = blockIdx.y;
    const float* H = g ? H1 : H0;
    int c = threadIdx.x & 15;
    float cv = cvec[g * 16 + c];
    int w = (blockIdx.x * blockDim.x + threadIdx.x) / 16;
    int stride = (gridDim.x * blockDim.x) / 16;
    float acc = 0.f;
    for (int node = w; node < n; node += stride) {
        float x = H[(size_t)node * 16 + c];
        float p = x * cv;
        p += __shfl_xor(p, 1, 16);
        p += __shfl_xor(p, 2, 16);
        p += __shfl_xor(p, 4, 16);
        p += __shfl_xor(p, 8, 16);
        float s = 1.f / (1.f + __expf(-p));
        acc += s * x;
    }
    __shared__ float sdata[TPB];
    sdata[threadIdx.x] = acc;
    __syncthreads();
    if (threadIdx.x < 16) {
        float s = 0.f;
        for (int t = threadIdx.x; t < TPB; t += 16) s += sdata[t];
        ppool[((size_t)g * gridDim.x + blockIdx.x) * 16 + threadIdx.x] = s;
    }
}

// ---------------- final: parallel reduce of pool partials + tensor-network scoring ----
// All 256 threads: coalesced float4 rep-reduce (8 iters) + LDS tree; bilinear split
// (p,t)-wise with unrolled coalesced Wt loads. No serialized runtime-bound load loops.

__global__ void final_kernel(const float* __restrict__ ppool, int nbp,
                             const float* __restrict__ Wt, const float* __restrict__ Wb,
                             const float* __restrict__ bt, const float* __restrict__ Wfc,
                             const float* __restrict__ bfc, const float* __restrict__ Wsc,
                             const float* __restrict__ bsc, float* __restrict__ out) {
    __shared__ float4 sd4[TPB];
    __shared__ float rep[32], part[TPB], scores[16], tvec[16];
    int t = threadIdx.x;
    // Phase A: rep[g*16+c] = sum over nbp blocks (parallel, coalesced)
    {
        const float4* p4 = (const float4*)ppool;
        int g = t >> 7;           // 0..1
        int r0 = (t >> 2) & 31;   // 0..31 row stripe
        int c4 = t & 3;           // channel quad
        float4 acc = make_float4(0.f, 0.f, 0.f, 0.f);
        for (int r = r0; r < nbp; r += 32)
            facc(acc, p4[((size_t)g * nbp + r) * 4 + c4]);
        sd4[t] = acc;
        __syncthreads();
        for (int st = 16; st >= 1; st >>= 1) {
            if (r0 < st) facc(sd4[t], sd4[t + st * 4]);
            __syncthreads();
        }
        if (r0 == 0) {
            float4 a = sd4[t];
            rep[g * 16 + c4 * 4 + 0] = a.x;
            rep[g * 16 + c4 * 4 + 1] = a.y;
            rep[g * 16 + c4 * 4 + 2] = a.z;
            rep[g * 16 + c4 * 4 + 3] = a.w;
        }
        __syncthreads();
    }
    // Phase B: bilinear partials — thread (p, tt): sum over q of e1[q]*Wt[(q*16+p)*16+tt]
    {
        int p = t >> 4, tt = t & 15;
        float b = 0.f;
#pragma unroll
        for (int q = 0; q < 16; q++)
            b += rep[q] * Wt[(q * 16 + p) * 16 + tt];
        part[t] = b * rep[16 + p];
    }
    __syncthreads();
    if (t < 16) {
        float bil = 0.f;
#pragma unroll
        for (int p = 0; p < 16; p++) bil += part[p * 16 + t];
        float blk = 0.f;
#pragma unroll
        for (int m = 0; m < 16; m++)
            blk += Wb[t * 32 + m] * rep[m] + Wb[t * 32 + 16 + m] * rep[16 + m];
        scores[t] = fmaxf(bil + blk + bt[t], 0.f);
    }
    __syncthreads();
    if (t < 16) {
        float acc = bfc[t];
#pragma unroll
        for (int k = 0; k < 16; k++) acc += scores[k] * Wfc[k * 16 + t];
        tvec[t] = tanhf(acc);
    }
    __syncthreads();
    if (t == 0) {
        float acc = bsc[0];
#pragma unroll
        for (int j = 0; j < 16; j++) acc += tvec[j] * Wsc[j];
        out[0] = 1.f / (1.f + __expf(-acc));
    }
}

// ---------------- launcher ----------------

extern "C" void kernel_launch(void* const* d_in, const int* in_sizes, int n_in,
                              void* d_out, int out_size, void* d_ws, size_t ws_size,
                              hipStream_t stream) {
    const float* X1 = (const float*)d_in[0];
    const float* X2 = (const float*)d_in[1];
    const int* edges1 = (const int*)d_in[2];
    const int* edges2 = (const int*)d_in[3];
    const float* W1 = (const float*)d_in[4];
    const float* b1 = (const float*)d_in[5];
    const float* W2 = (const float*)d_in[6];
    const float* b2 = (const float*)d_in[7];
    const float* W3 = (const float*)d_in[8];
    const float* b3 = (const float*)d_in[9];
    const float* Wa = (const float*)d_in[10];
    const float* Wt = (const float*)d_in[11];
    const float* Wb = (const float*)d_in[12];
    const float* bt = (const float*)d_in[13];
    const float* Wfc = (const float*)d_in[14];
    const float* bfc = (const float*)d_in[15];
    const float* Wsc = (const float*)d_in[16];
    const float* bsc = (const float*)d_in[17];
    float* out = (float*)d_out;

    const int N = in_sizes[0] / 96;
    const int E = in_sizes[2] / 2;
    const int NBUK = (N + BW - 1) / BW;  // buckets (must be <= 1024)

    char* ws = (char*)d_ws;
    size_t o = 0;
    auto alloc = [&](size_t bytes) {
        void* p = ws + o;
        o += (bytes + 255) & ~(size_t)255;
        return p;
    };
    int* bcnt = (int*)alloc((size_t)2 * 1024 * 4);
    int* boff = (int*)alloc((size_t)2 * 1024 * 4);
    int* bcur = (int*)alloc((size_t)2 * 1024 * 4);
    int* off0 = (int*)alloc((size_t)(N + 1) * 4);
    int* off1 = (int*)alloc((size_t)(N + 1) * 4);
    int* col0 = (int*)alloc((size_t)E * 4);
    int* col1 = (int*)alloc((size_t)E * 4);
    float* dinv0 = (float*)alloc((size_t)N * 4);
    float* dinv1 = (float*)alloc((size_t)N * 4);
    int* ebuf0 = (int*)alloc((size_t)E * 4);
    int* ebuf1 = (int*)alloc((size_t)E * 4);
    u16* hwb0 = (u16*)alloc((size_t)N * 64 * 2);   // bf16 gather payload
    u16* hwb1 = (u16*)alloc((size_t)N * 64 * 2);
    float* bufB0 = (float*)alloc((size_t)N * 64 * 4);  // fp32 agg outputs
    float* bufB1 = (float*)alloc((size_t)N * 64 * 4);

    const int gB1 = (E + 8191) / 8192;
    const int gB2 = (E + 4095) / 4096;
    const int g16 = ((size_t)N * 16 + TPB - 1) / TPB;  // all aggs run 16 threads/node
    const int gMM = (N + 63) / 64;                     // MFMA matmul: 64 nodes/block
    const int gPool = 256;                             // pool blocks per graph

    float* pcol = (float*)alloc((size_t)2 * g16 * 16 * 4);   // agg16 colsum partials
    float* cvecArr = (float*)alloc(32 * 4);
    float* ppool = (float*)alloc((size_t)2 * gPool * 16 * 4);

    hipMemsetAsync(bcnt, 0, (size_t)2 * 1024 * 4, stream);

    // bucketed CSR build (both graphs per dispatch)
    bucket_count_kernel<<<dim3(gB1, 2), TPB, 0, stream>>>(edges1 + E, edges2 + E, E, bcnt, NBUK);
    bucket_scan_kernel<<<2, 1024, 0, stream>>>(bcnt, NBUK, boff, bcur);
    bucket_scatter_kernel<<<dim3(gB2, 2), TPB, 0, stream>>>(edges1, edges2, E, bcur, ebuf0, ebuf1, NBUK);
    bucket_csr_kernel<<<dim3(NBUK, 2), TPB, 0, stream>>>(ebuf0, ebuf1, boff, bcnt, N, E,
                                                         off0, off1, dinv0, dinv1, col0, col1);

    // layer 1: 96 -> 64 (MFMA), agg + relu (SPLIT=1: 16 threads/node)
    matmul_kernel<96, 64><<<dim3(gMM, 2), TPB, 0, stream>>>(X1, X2, W1, dinv0, dinv1, hwb0, hwb1, N);
    agg_kernel<64, 1, true><<<dim3(g16, 2), TPB, 0, stream>>>(
        hwb0, hwb1, off0, off1, col0, col1, dinv0, dinv1, b1, bufB0, bufB1, N);
    // layer 2: 64 -> 32 (MFMA), agg + relu (SPLIT=2)
    matmul_kernel<64, 32><<<dim3(gMM, 2), TPB, 0, stream>>>(bufB0, bufB1, W2, dinv0, dinv1, hwb0, hwb1, N);
    agg_kernel<32, 2, true><<<dim3(g16, 2), TPB, 0, stream>>>(
        hwb0, hwb1, off0, off1, col0, col1, dinv0, dinv1, b2, bufB0, bufB1, N);
    // layer 3: 32 -> 16 (MFMA), agg + colsum partials (SPLIT=4)
    matmul_kernel<32, 16><<<dim3(gMM, 2), TPB, 0, stream>>>(bufB0, bufB1, W3, dinv0, dinv1, hwb0, hwb1, N);
    agg16_kernel<<<dim3(g16, 2), TPB, 0, stream>>>(
        hwb0, hwb1, off0, off1, col0, col1, dinv0, dinv1, b3, bufB0, bufB1, pcol, N);

    // attention pooling: coalesced cvec reduce, then high-occupancy pool partials
    cvec_kernel<<<2, TPB, 0, stream>>>(pcol, g16, 1.0f / (float)N, Wa, cvecArr);
    pool_kernel<<<dim3(gPool, 2), TPB, 0, stream>>>(bufB0, bufB1, N, cvecArr, ppool);
    final_kernel<<<1, 256, 0, stream>>>(ppool, gPool, Wt, Wb, bt, Wfc, bfc, Wsc, bsc, out);
}

// Round 15
// 269.484 us; speedup vs baseline: 6.1387x; 1.0531x over previous
//
#include <hip/hip_runtime.h>
#include <hip/hip_bf16.h>

#define TPB 256
#define SH 6
#define BW 64  // nodes per bucket = 1<<SH; NBUK must be <= 1024 (N <= 65536)

typedef unsigned short u16;
typedef __attribute__((ext_vector_type(8))) __bf16 bf16x8;  // MFMA A/B frag (4 VGPRs)
typedef __attribute__((ext_vector_type(4))) float f32x4;    // MFMA C/D frag

// bf16 helpers: payload stored as bf16 (halves gather BW), accumulate in fp32.
__device__ __forceinline__ u16 f_to_bf(float f) {
    unsigned u = __float_as_uint(f);
    return (u16)((u + 0x7fff + ((u >> 16) & 1)) >> 16);  // RNE
}
__device__ __forceinline__ float4 bf4_to_f4(ushort4 v) {
    float4 r;
    r.x = __uint_as_float((unsigned)v.x << 16);
    r.y = __uint_as_float((unsigned)v.y << 16);
    r.z = __uint_as_float((unsigned)v.z << 16);
    r.w = __uint_as_float((unsigned)v.w << 16);
    return r;
}
__device__ __forceinline__ void facc(float4& a, float4 v) {
    a.x += v.x; a.y += v.y; a.z += v.z; a.w += v.w;
}
__device__ __forceinline__ float4 shfl_xor4(float4 v, int mask, int width) {
    v.x = __shfl_xor(v.x, mask, width);
    v.y = __shfl_xor(v.y, mask, width);
    v.z = __shfl_xor(v.z, mask, width);
    v.w = __shfl_xor(v.w, mask, width);
    return v;
}

template <int C>
__device__ __forceinline__ float4 gather_sum(const u16* __restrict__ HW,
                                             const int* __restrict__ col,
                                             int c0, int ps, int pe) {
    float4 a0 = make_float4(0.f, 0.f, 0.f, 0.f);
    float4 a1 = a0, a2 = a0, a3 = a0;
    int p = ps;
    for (; p + 4 <= pe; p += 4) {
        int j0 = col[p], j1 = col[p + 1], j2 = col[p + 2], j3 = col[p + 3];
        facc(a0, bf4_to_f4(*(const ushort4*)&HW[(size_t)j0 * C + c0]));
        facc(a1, bf4_to_f4(*(const ushort4*)&HW[(size_t)j1 * C + c0]));
        facc(a2, bf4_to_f4(*(const ushort4*)&HW[(size_t)j2 * C + c0]));
        facc(a3, bf4_to_f4(*(const ushort4*)&HW[(size_t)j3 * C + c0]));
    }
    for (; p < pe; p++) {
        int j = col[p];
        facc(a0, bf4_to_f4(*(const ushort4*)&HW[(size_t)j * C + c0]));
    }
    facc(a0, a1); facc(a2, a3); facc(a0, a2);
    return a0;
}

// ---------------- capacity-bucket CSR build (no count/scan passes) ----------------
// Bucket b owns region [b*cap, (b+1)*cap) of ebuf/col. bcur is zero-initialized;
// scatter reserves runs per block via one atomicAdd per touched bucket.

__global__ void bucket_scatter_kernel(const int* __restrict__ e0, const int* __restrict__ e1,
                                      int E, int* __restrict__ bcur,
                                      int* __restrict__ ebuf0, int* __restrict__ ebuf1,
                                      int nbuk, int cap) {
    int g = blockIdx.y;
    const int* src = g ? e1 : e0;
    const int* dst = src + E;
    int* ebuf = g ? ebuf1 : ebuf0;
    int* bu = bcur + g * 1024;
    __shared__ int hist[1024];
    for (int t = threadIdx.x; t < 1024; t += TPB) hist[t] = 0;
    __syncthreads();
    int base = blockIdx.x * 4096;
    int pk[16], bk[16], rk[16];
#pragma unroll
    for (int k = 0; k < 16; k++) {
        int e = base + k * TPB + (int)threadIdx.x;
        bk[k] = -1;
        if (e < E) {
            int s = src[e], d = dst[e];
            int b = d >> SH;
            bk[k] = b;
            pk[k] = (s << SH) | (d & (BW - 1));
            rk[k] = atomicAdd(&hist[b], 1);
        }
    }
    __syncthreads();
    for (int t = threadIdx.x; t < nbuk; t += TPB) {
        int h = hist[t];
        hist[t] = h ? atomicAdd(&bu[t], h) : 0;
    }
    __syncthreads();
#pragma unroll
    for (int k = 0; k < 16; k++)
        if (bk[k] >= 0) {
            int pos = hist[bk[k]] + rk[k];
            if (pos < cap) ebuf[(size_t)bk[k] * cap + pos] = pk[k];
        }
}

// Per-bucket: histogram -> local scan -> soff/eoff/dinv -> fill col (bucket-local).
__global__ void bucket_csr_kernel(const int* __restrict__ ebuf0, const int* __restrict__ ebuf1,
                                  const int* __restrict__ bcur, int n, int cap,
                                  int* __restrict__ soff0, int* __restrict__ soff1,
                                  int* __restrict__ eoff0, int* __restrict__ eoff1,
                                  float* __restrict__ dinv0, float* __restrict__ dinv1,
                                  int* __restrict__ col0, int* __restrict__ col1) {
    int g = blockIdx.y;
    int b = blockIdx.x;
    const int* ebuf = g ? ebuf1 : ebuf0;
    int* soff = g ? soff1 : soff0;
    int* eoff = g ? eoff1 : eoff0;
    float* dinv = g ? dinv1 : dinv0;
    int* col = g ? col1 : col0;
    __shared__ int h[BW], nb[BW], nrank[BW];
    int tid = threadIdx.x;
    if (tid < BW) h[tid] = 0;
    __syncthreads();
    int s = b * cap;
    int cnt = min(bcur[g * 1024 + b], cap);
    int e = s + cnt;
    for (int i = s + tid; i < e; i += TPB)
        atomicAdd(&h[ebuf[i] & (BW - 1)], 1);
    __syncthreads();
    if (tid < BW) {
        int v = h[tid];
        int x = v;
        for (int d = 1; d < BW; d <<= 1) {
            int u = __shfl_up(x, d, 64);
            if (tid >= d) x += u;
        }
        int base = s + x - v;  // exclusive prefix within bucket region
        nb[tid] = base;
        nrank[tid] = 0;
        int node = b * BW + tid;
        if (node < n) {
            soff[node] = base;
            eoff[node] = base + v;
            dinv[node] = rsqrtf((float)v + 1.0f);
        }
    }
    __syncthreads();
    for (int i = s + tid; i < e; i += TPB) {
        int p = ebuf[i];
        int lo = p & (BW - 1);
        int r = atomicAdd(&nrank[lo], 1);
        col[nb[lo] + r] = p >> SH;
    }
}

// ---------------- dense matmul via MFMA: Y = bf16( dinv[n] * (X @ W) ) ----------

template <int CIN, int COUT>
__global__ void matmul_kernel(const float* __restrict__ X0, const float* __restrict__ X1,
                              const float* __restrict__ W,
                              const float* __restrict__ dinv0, const float* __restrict__ dinv1,
                              u16* __restrict__ Y0, u16* __restrict__ Y1, int n) {
    constexpr int CINP = CIN + 8;
    constexpr int NT = COUT / 16;
    constexpr int KT = CIN / 32;
    __shared__ u16 Xs[64 * CINP];
    __shared__ u16 Wt[COUT * CINP];

    int g = blockIdx.y;
    const float* X = g ? X1 : X0;
    const float* dinv = g ? dinv1 : dinv0;
    u16* Y = g ? Y1 : Y0;
    int nb0 = blockIdx.x * 64;

    for (int i = threadIdx.x; i < 64 * (CIN / 4); i += TPB) {
        int nn = i / (CIN / 4), kc = i % (CIN / 4);
        float4 v = make_float4(0.f, 0.f, 0.f, 0.f);
        if (nb0 + nn < n) v = *(const float4*)&X[(size_t)(nb0 + nn) * CIN + 4 * kc];
        ushort4 b;
        b.x = f_to_bf(v.x); b.y = f_to_bf(v.y); b.z = f_to_bf(v.z); b.w = f_to_bf(v.w);
        *(ushort4*)&Xs[nn * CINP + 4 * kc] = b;
    }
    for (int i = threadIdx.x; i < CIN * (COUT / 4); i += TPB) {
        int k = i / (COUT / 4), nc4 = i % (COUT / 4);
        float4 v = *(const float4*)&W[(size_t)k * COUT + 4 * nc4];
        Wt[(4 * nc4 + 0) * CINP + k] = f_to_bf(v.x);
        Wt[(4 * nc4 + 1) * CINP + k] = f_to_bf(v.y);
        Wt[(4 * nc4 + 2) * CINP + k] = f_to_bf(v.z);
        Wt[(4 * nc4 + 3) * CINP + k] = f_to_bf(v.w);
    }
    __syncthreads();

    int lane = threadIdx.x & 63;
    int w = threadIdx.x >> 6;
    int m = lane & 15;
    int quad = lane >> 4;

    f32x4 acc[NT];
#pragma unroll
    for (int t = 0; t < NT; t++) acc[t] = (f32x4){0.f, 0.f, 0.f, 0.f};
#pragma unroll
    for (int kt = 0; kt < KT; kt++) {
        int k0 = kt * 32 + quad * 8;
        bf16x8 a = *(const bf16x8*)&Xs[(w * 16 + m) * CINP + k0];
#pragma unroll
        for (int t = 0; t < NT; t++) {
            bf16x8 b = *(const bf16x8*)&Wt[(t * 16 + m) * CINP + k0];
            acc[t] = __builtin_amdgcn_mfma_f32_16x16x32_bf16(a, b, acc[t], 0, 0, 0);
        }
    }
#pragma unroll
    for (int r = 0; r < 4; r++) {
        int node = nb0 + w * 16 + quad * 4 + r;
        if (node < n) {
            float d = dinv[node];
#pragma unroll
            for (int t = 0; t < NT; t++)
                Y[(size_t)node * COUT + t * 16 + m] = f_to_bf(acc[t][r] * d);
        }
    }
}

// ------- fused GCN agg (C channels, bf16 payload) + next-layer matmul epilogue -------
// Block = 16 nodes (TPN=16 threads/node). Gather+relu produces H rows in LDS; then
// the same block computes Y = bf16(dinv * (H @ W2)) [COUT2 channels] -- fusing the
// next layer's matmul and eliminating the fp32 H round-trip through HBM.

template <int C, int SPLIT, int COUT2>
__global__ void agg_mm_kernel(const u16* __restrict__ HW0, const u16* __restrict__ HW1,
                              const int* __restrict__ soff0, const int* __restrict__ soff1,
                              const int* __restrict__ eoff0, const int* __restrict__ eoff1,
                              const int* __restrict__ col0, const int* __restrict__ col1,
                              const float* __restrict__ dinv0, const float* __restrict__ dinv1,
                              const float* __restrict__ bias, const float* __restrict__ W2,
                              u16* __restrict__ Y0, u16* __restrict__ Y1, int n) {
    constexpr int CH = C / 4;
    constexpr int TPN = CH * SPLIT;        // 16
    constexpr int HS = C + 4;              // padded H row stride (floats)
    constexpr int OPT = 16 * COUT2 / TPB;  // outputs per thread (2 or 1)
    __shared__ float Ws2[C * COUT2];
    __shared__ float Hs[16 * HS];

    int g = blockIdx.y;
    const u16* HW = g ? HW1 : HW0;
    const int* soff = g ? soff1 : soff0;
    const int* eoff = g ? eoff1 : eoff0;
    const int* col = g ? col1 : col0;
    const float* dinv = g ? dinv1 : dinv0;
    u16* Y = g ? Y1 : Y0;

    // stage W2 (fp32) while gather loads are in flight
    for (int i = threadIdx.x; i < C * COUT2 / 4; i += TPB)
        ((float4*)Ws2)[i] = ((const float4*)W2)[i];

    int tid = blockIdx.x * TPB + (int)threadIdx.x;
    int node = tid / TPN;
    int nl = threadIdx.x / TPN;
    int part = threadIdx.x % TPN;
    int sp = part / CH;
    int c0 = (part % CH) * 4;
    float4 o = make_float4(0.f, 0.f, 0.f, 0.f);
    if (node < n) {
        int s = soff[node], e = eoff[node];
        int len = e - s;
        int chunk = (len + SPLIT - 1) / SPLIT;
        int ps = s + sp * chunk;
        int pe = min(ps + chunk, e);
        float4 r = gather_sum<C>(HW, col, c0, ps, pe);
#pragma unroll
        for (int m = CH; m < TPN; m <<= 1) facc(r, shfl_xor4(r, m, TPN));
        if (sp == 0) {
            float di = dinv[node];
            float4 self = bf4_to_f4(*(const ushort4*)&HW[(size_t)node * C + c0]);
            float4 b4 = *(const float4*)&bias[c0];
            o.x = fmaxf(di * (r.x + self.x) + b4.x, 0.f);
            o.y = fmaxf(di * (r.y + self.y) + b4.y, 0.f);
            o.z = fmaxf(di * (r.z + self.z) + b4.z, 0.f);
            o.w = fmaxf(di * (r.w + self.w) + b4.w, 0.f);
        }
    }
    if (sp == 0) *(float4*)&Hs[nl * HS + c0] = o;  // zeros for tail nodes
    __syncthreads();

    // matmul epilogue: node nl2, output channels p2*OPT..+OPT-1
    int nl2 = threadIdx.x >> 4;
    int p2 = threadIdx.x & 15;
    int onode = blockIdx.x * 16 + nl2;
    if (onode < n) {
        float d = dinv[onode];
        float acc[OPT];
#pragma unroll
        for (int j = 0; j < OPT; j++) acc[j] = 0.f;
#pragma unroll
        for (int k = 0; k < C; k++) {
            float h = Hs[nl2 * HS + k];
#pragma unroll
            for (int j = 0; j < OPT; j++)
                acc[j] += h * Ws2[k * COUT2 + p2 * OPT + j];
        }
        if constexpr (OPT == 2) {
            unsigned pack = (unsigned)f_to_bf(acc[0] * d) | ((unsigned)f_to_bf(acc[1] * d) << 16);
            *(unsigned*)&Y[(size_t)onode * COUT2 + p2 * 2] = pack;
        } else {
            Y[(size_t)onode * COUT2 + p2] = f_to_bf(acc[0] * d);
        }
    }
}

// Layer-3 aggregation (C=16, SPLIT=4) + per-block colsum partials (NO atomics).
__global__ void agg16_kernel(const u16* __restrict__ HW0, const u16* __restrict__ HW1,
                             const int* __restrict__ soff0, const int* __restrict__ soff1,
                             const int* __restrict__ eoff0, const int* __restrict__ eoff1,
                             const int* __restrict__ col0, const int* __restrict__ col1,
                             const float* __restrict__ dinv0, const float* __restrict__ dinv1,
                             const float* __restrict__ bias,
                             float* __restrict__ out0, float* __restrict__ out1,
                             float* __restrict__ pcol, int n) {
    int g = blockIdx.y;
    const u16* HW = g ? HW1 : HW0;
    const int* soff = g ? soff1 : soff0;
    const int* eoff = g ? eoff1 : eoff0;
    const int* col = g ? col1 : col0;
    const float* dinv = g ? dinv1 : dinv0;
    float* outp = g ? out1 : out0;
    int tid = blockIdx.x * blockDim.x + threadIdx.x;
    int node = tid / 16;
    int part = tid % 16;
    int sp = part / 4;
    int c0 = (part % 4) * 4;
    float4 o = make_float4(0.f, 0.f, 0.f, 0.f);
    if (node < n) {
        int s = soff[node], e = eoff[node];
        int len = e - s;
        int chunk = (len + 3) / 4;
        int ps = s + sp * chunk;
        int pe = min(ps + chunk, e);
        float4 r = gather_sum<16>(HW, col, c0, ps, pe);
        facc(r, shfl_xor4(r, 4, 16));
        facc(r, shfl_xor4(r, 8, 16));
        if (sp == 0) {
            float di = dinv[node];
            float4 self = bf4_to_f4(*(const ushort4*)&HW[(size_t)node * 16 + c0]);
            float4 b4 = *(const float4*)&bias[c0];
            o.x = di * (r.x + self.x) + b4.x;
            o.y = di * (r.y + self.y) + b4.y;
            o.z = di * (r.z + self.z) + b4.z;
            o.w = di * (r.w + self.w) + b4.w;
            *(float4*)&outp[(size_t)node * 16 + c0] = o;
        }
    }
    // per-block colsum partial (only sp==0 lanes hold data)
    __shared__ float4 sd[TPB];
    sd[threadIdx.x] = (node < n && sp == 0) ? o : make_float4(0.f, 0.f, 0.f, 0.f);
    __syncthreads();
    if (threadIdx.x < 64) {
        float4 a = sd[threadIdx.x];
        facc(a, sd[threadIdx.x + 64]);
        facc(a, sd[threadIdx.x + 128]);
        facc(a, sd[threadIdx.x + 192]);
        sd[threadIdx.x] = a;
    }
    __syncthreads();
    if (threadIdx.x < 16) {
        float4 a = sd[threadIdx.x];
        facc(a, sd[threadIdx.x + 16]);
        facc(a, sd[threadIdx.x + 32]);
        facc(a, sd[threadIdx.x + 48]);
        sd[threadIdx.x] = a;
    }
    __syncthreads();
    if (threadIdx.x < 4)
        *(float4*)&pcol[((size_t)g * gridDim.x + blockIdx.x) * 16 + threadIdx.x * 4] = sd[threadIdx.x];
}

// ---------------- cvec: coalesced reduce of pcol partials + tanh(mean @ Wa) ----------

__global__ void cvec_kernel(const float* __restrict__ pcol, int nb16, float n_inv,
                            const float* __restrict__ Wa, float* __restrict__ cvec) {
    int g = blockIdx.x;
    const float4* p4 = (const float4*)(pcol + (size_t)g * nb16 * 16);
    __shared__ float4 sd[TPB];
    __shared__ float cs[16];
    int c4 = threadIdx.x & 3;
    int row = threadIdx.x >> 2;
    float4 acc = make_float4(0.f, 0.f, 0.f, 0.f);
    for (int r = row; r < nb16; r += 64) facc(acc, p4[(size_t)r * 4 + c4]);
    sd[threadIdx.x] = acc;
    __syncthreads();
    if (threadIdx.x < 64) {
        float4 a = sd[threadIdx.x];
        facc(a, sd[threadIdx.x + 64]);
        facc(a, sd[threadIdx.x + 128]);
        facc(a, sd[threadIdx.x + 192]);
        sd[threadIdx.x] = a;
    }
    __syncthreads();
    if (threadIdx.x < 16) {
        float4 a = sd[threadIdx.x];
        facc(a, sd[threadIdx.x + 16]);
        facc(a, sd[threadIdx.x + 32]);
        facc(a, sd[threadIdx.x + 48]);
        sd[threadIdx.x] = a;
    }
    __syncthreads();
    if (threadIdx.x < 4) {
        float4 a = sd[threadIdx.x];
        facc(a, sd[threadIdx.x + 4]);
        facc(a, sd[threadIdx.x + 8]);
        facc(a, sd[threadIdx.x + 12]);
        cs[threadIdx.x * 4 + 0] = a.x * n_inv;
        cs[threadIdx.x * 4 + 1] = a.y * n_inv;
        cs[threadIdx.x * 4 + 2] = a.z * n_inv;
        cs[threadIdx.x * 4 + 3] = a.w * n_inv;
    }
    __syncthreads();
    if (threadIdx.x < 16) {
        float acc2 = 0.f;
#pragma unroll
        for (int i = 0; i < 16; i++) acc2 += cs[i] * Wa[i * 16 + threadIdx.x];
        cvec[g * 16 + threadIdx.x] = tanhf(acc2);
    }
}

// ---------------- attention pooling (per-block partials, no atomics) ----------------

__global__ void pool_kernel(const float* __restrict__ H0, const float* __restrict__ H1, int n,
                            const float* __restrict__ cvec, float* __restrict__ ppool) {
    int g = blockIdx.y;
    const float* H = g ? H1 : H0;
    int c = threadIdx.x & 15;
    float cv = cvec[g * 16 + c];
    int w = (blockIdx.x * blockDim.x + threadIdx.x) / 16;
    int stride = (gridDim.x * blockDim.x) / 16;
    float acc = 0.f;
    for (int node = w; node < n; node += stride) {
        float x = H[(size_t)node * 16 + c];
        float p = x * cv;
        p += __shfl_xor(p, 1, 16);
        p += __shfl_xor(p, 2, 16);
        p += __shfl_xor(p, 4, 16);
        p += __shfl_xor(p, 8, 16);
        float s = 1.f / (1.f + __expf(-p));
        acc += s * x;
    }
    __shared__ float sdata[TPB];
    sdata[threadIdx.x] = acc;
    __syncthreads();
    if (threadIdx.x < 16) {
        float s = 0.f;
        for (int t = threadIdx.x; t < TPB; t += 16) s += sdata[t];
        ppool[((size_t)g * gridDim.x + blockIdx.x) * 16 + threadIdx.x] = s;
    }
}

// ---------------- final: parallel reduce of pool partials + tensor-network scoring ----

__global__ void final_kernel(const float* __restrict__ ppool, int nbp,
                             const float* __restrict__ Wt, const float* __restrict__ Wb,
                             const float* __restrict__ bt, const float* __restrict__ Wfc,
                             const float* __restrict__ bfc, const float* __restrict__ Wsc,
                             const float* __restrict__ bsc, float* __restrict__ out) {
    __shared__ float4 sd4[TPB];
    __shared__ float rep[32], part[TPB], scores[16], tvec[16];
    int t = threadIdx.x;
    {
        const float4* p4 = (const float4*)ppool;
        int g = t >> 7;
        int r0 = (t >> 2) & 31;
        int c4 = t & 3;
        float4 acc = make_float4(0.f, 0.f, 0.f, 0.f);
        for (int r = r0; r < nbp; r += 32)
            facc(acc, p4[((size_t)g * nbp + r) * 4 + c4]);
        sd4[t] = acc;
        __syncthreads();
        for (int st = 16; st >= 1; st >>= 1) {
            if (r0 < st) facc(sd4[t], sd4[t + st * 4]);
            __syncthreads();
        }
        if (r0 == 0) {
            float4 a = sd4[t];
            rep[g * 16 + c4 * 4 + 0] = a.x;
            rep[g * 16 + c4 * 4 + 1] = a.y;
            rep[g * 16 + c4 * 4 + 2] = a.z;
            rep[g * 16 + c4 * 4 + 3] = a.w;
        }
        __syncthreads();
    }
    {
        int p = t >> 4, tt = t & 15;
        float b = 0.f;
#pragma unroll
        for (int q = 0; q < 16; q++)
            b += rep[q] * Wt[(q * 16 + p) * 16 + tt];
        part[t] = b * rep[16 + p];
    }
    __syncthreads();
    if (t < 16) {
        float bil = 0.f;
#pragma unroll
        for (int p = 0; p < 16; p++) bil += part[p * 16 + t];
        float blk = 0.f;
#pragma unroll
        for (int m = 0; m < 16; m++)
            blk += Wb[t * 32 + m] * rep[m] + Wb[t * 32 + 16 + m] * rep[16 + m];
        scores[t] = fmaxf(bil + blk + bt[t], 0.f);
    }
    __syncthreads();
    if (t < 16) {
        float acc = bfc[t];
#pragma unroll
        for (int k = 0; k < 16; k++) acc += scores[k] * Wfc[k * 16 + t];
        tvec[t] = tanhf(acc);
    }
    __syncthreads();
    if (t == 0) {
        float acc = bsc[0];
#pragma unroll
        for (int j = 0; j < 16; j++) acc += tvec[j] * Wsc[j];
        out[0] = 1.f / (1.f + __expf(-acc));
    }
}

// ---------------- launcher ----------------

extern "C" void kernel_launch(void* const* d_in, const int* in_sizes, int n_in,
                              void* d_out, int out_size, void* d_ws, size_t ws_size,
                              hipStream_t stream) {
    const float* X1 = (const float*)d_in[0];
    const float* X2 = (const float*)d_in[1];
    const int* edges1 = (const int*)d_in[2];
    const int* edges2 = (const int*)d_in[3];
    const float* W1 = (const float*)d_in[4];
    const float* b1 = (const float*)d_in[5];
    const float* W2 = (const float*)d_in[6];
    const float* b2 = (const float*)d_in[7];
    const float* W3 = (const float*)d_in[8];
    const float* b3 = (const float*)d_in[9];
    const float* Wa = (const float*)d_in[10];
    const float* Wt = (const float*)d_in[11];
    const float* Wb = (const float*)d_in[12];
    const float* bt = (const float*)d_in[13];
    const float* Wfc = (const float*)d_in[14];
    const float* bfc = (const float*)d_in[15];
    const float* Wsc = (const float*)d_in[16];
    const float* bsc = (const float*)d_in[17];
    float* out = (float*)d_out;

    const int N = in_sizes[0] / 96;
    const int E = in_sizes[2] / 2;
    const int NBUK = (N + BW - 1) / BW;  // buckets (must be <= 1024)
    int cap = ((2 * (E / NBUK)) + 255) & ~255;  // bucket capacity: 2x average, safe
    if (cap < 256) cap = 256;

    char* ws = (char*)d_ws;
    size_t o = 0;
    auto alloc = [&](size_t bytes) {
        void* p = ws + o;
        o += (bytes + 255) & ~(size_t)255;
        return p;
    };
    int* bcur = (int*)alloc((size_t)2 * 1024 * 4);
    int* soff0 = (int*)alloc((size_t)N * 4);
    int* soff1 = (int*)alloc((size_t)N * 4);
    int* eoff0 = (int*)alloc((size_t)N * 4);
    int* eoff1 = (int*)alloc((size_t)N * 4);
    int* col0 = (int*)alloc((size_t)NBUK * cap * 4);
    int* col1 = (int*)alloc((size_t)NBUK * cap * 4);
    int* ebuf0 = (int*)alloc((size_t)NBUK * cap * 4);
    int* ebuf1 = (int*)alloc((size_t)NBUK * cap * 4);
    float* dinv0 = (float*)alloc((size_t)N * 4);
    float* dinv1 = (float*)alloc((size_t)N * 4);
    u16* hwbA0 = (u16*)alloc((size_t)N * 64 * 2);  // layer-1 payload
    u16* hwbA1 = (u16*)alloc((size_t)N * 64 * 2);
    u16* hwbB0 = (u16*)alloc((size_t)N * 32 * 2);  // layer-2 payload
    u16* hwbB1 = (u16*)alloc((size_t)N * 32 * 2);
    u16* hwbC0 = (u16*)alloc((size_t)N * 16 * 2);  // layer-3 payload
    u16* hwbC1 = (u16*)alloc((size_t)N * 16 * 2);
    float* H30 = (float*)alloc((size_t)N * 16 * 4);  // H3 fp32 (pool input)
    float* H31 = (float*)alloc((size_t)N * 16 * 4);

    const int gB2 = (E + 4095) / 4096;
    const int g16 = ((size_t)N * 16 + TPB - 1) / TPB;  // aggs: 16 threads/node
    const int gMM = (N + 63) / 64;
    const int gPool = 256;

    float* pcol = (float*)alloc((size_t)2 * g16 * 16 * 4);
    float* cvecArr = (float*)alloc(32 * 4);
    float* ppool = (float*)alloc((size_t)2 * gPool * 16 * 4);

    hipMemsetAsync(bcur, 0, (size_t)2 * 1024 * 4, stream);

    // capacity-bucket CSR build: scatter -> per-bucket finalize (no count/scan passes)
    bucket_scatter_kernel<<<dim3(gB2, 2), TPB, 0, stream>>>(edges1, edges2, E, bcur,
                                                            ebuf0, ebuf1, NBUK, cap);
    bucket_csr_kernel<<<dim3(NBUK, 2), TPB, 0, stream>>>(ebuf0, ebuf1, bcur, N, cap,
                                                         soff0, soff1, eoff0, eoff1,
                                                         dinv0, dinv1, col0, col1);

    // layer 1 matmul (MFMA 96->64)
    matmul_kernel<96, 64><<<dim3(gMM, 2), TPB, 0, stream>>>(X1, X2, W1, dinv0, dinv1, hwbA0, hwbA1, N);
    // layer-1 agg + fused layer-2 matmul (64 -> H1 -> @W2 -> 32 bf16)
    agg_mm_kernel<64, 1, 32><<<dim3(g16, 2), TPB, 0, stream>>>(
        hwbA0, hwbA1, soff0, soff1, eoff0, eoff1, col0, col1, dinv0, dinv1, b1, W2, hwbB0, hwbB1, N);
    // layer-2 agg + fused layer-3 matmul (32 -> H2 -> @W3 -> 16 bf16)
    agg_mm_kernel<32, 2, 16><<<dim3(g16, 2), TPB, 0, stream>>>(
        hwbB0, hwbB1, soff0, soff1, eoff0, eoff1, col0, col1, dinv0, dinv1, b2, W3, hwbC0, hwbC1, N);
    // layer-3 agg (writes H3 fp32 + colsum partials)
    agg16_kernel<<<dim3(g16, 2), TPB, 0, stream>>>(
        hwbC0, hwbC1, soff0, soff1, eoff0, eoff1, col0, col1, dinv0, dinv1, b3, H30, H31, pcol, N);

    // attention pooling + scoring
    cvec_kernel<<<2, TPB, 0, stream>>>(pcol, g16, 1.0f / (float)N, Wa, cvecArr);
    pool_kernel<<<dim3(gPool, 2), TPB, 0, stream>>>(H30, H31, N, cvecArr, ppool);
    final_kernel<<<1, 256, 0, stream>>>(ppool, gPool, Wt, Wb, bt, Wfc, bfc, Wsc, bsc, out);
}